// Round 3
// baseline (4001.040 us; speedup 1.0000x reference)
//
#include <hip/hip_runtime.h>
#include <cstddef>
#include <cstdint>

#define NH 9

typedef _Float16 f16x8 __attribute__((ext_vector_type(8)));
typedef float f32x4 __attribute__((ext_vector_type(4)));

static const int cN1 = 100000, cN2 = 25000, cN3 = 6250;
static const int cE1 = 1200000, cE2 = 300000, cE3 = 75000;

static inline unsigned ceil_div(size_t a, size_t b) { return (unsigned)((a + b - 1) / b); }

// ---------------- generic fp32 GEMM: C[M,N] = A[M,K](lda) @ B[K,N](ldb) ----------------
__global__ __launch_bounds__(256) void gemm_f32(
    const float* __restrict__ A, int lda,
    const float* __restrict__ B, int ldb,
    float* __restrict__ C, int ldc,
    int M, int N, int K)
{
    const int BM = 64, BN = 64, BK = 16;
    __shared__ float As[BK][BM + 1];
    __shared__ float Bs[BK][BN + 1];
    const int tid = threadIdx.x;
    const int tx = tid & 15, ty = tid >> 4;
    const int row0 = blockIdx.y * BM, col0 = blockIdx.x * BN;
    float acc[4][4] = {};
    for (int k0 = 0; k0 < K; k0 += BK) {
        for (int l = tid; l < BM * BK; l += 256) {
            int r = l >> 4, c = l & 15;
            float v = 0.f;
            if (row0 + r < M && k0 + c < K) v = A[(size_t)(row0 + r) * lda + (k0 + c)];
            As[c][r] = v;
        }
        for (int l = tid; l < BK * BN; l += 256) {
            int r = l >> 6, c = l & 63;
            float v = 0.f;
            if (k0 + r < K && col0 + c < N) v = B[(size_t)(k0 + r) * ldb + (col0 + c)];
            Bs[r][c] = v;
        }
        __syncthreads();
#pragma unroll
        for (int kk = 0; kk < BK; ++kk) {
            float a[4], b[4];
#pragma unroll
            for (int i = 0; i < 4; ++i) a[i] = As[kk][ty * 4 + i];
#pragma unroll
            for (int j = 0; j < 4; ++j) b[j] = Bs[kk][tx * 4 + j];
#pragma unroll
            for (int i = 0; i < 4; ++i)
#pragma unroll
                for (int j = 0; j < 4; ++j) acc[i][j] += a[i] * b[j];
        }
        __syncthreads();
    }
#pragma unroll
    for (int i = 0; i < 4; ++i) {
        int r = row0 + ty * 4 + i;
        if (r >= M) break;
#pragma unroll
        for (int j = 0; j < 4; ++j) {
            int c = col0 + tx * 4 + j;
            if (c < N) C[(size_t)r * ldc + c] = acc[i][j];
        }
    }
}

// ---------------- sorting: count / scan / scatter ----------------
__global__ void count_idx(const int* __restrict__ idx, int n, int* __restrict__ cnt)
{
    int i = blockIdx.x * 256 + threadIdx.x;
    if (i < n) atomicAdd(&cnt[idx[i]], 1);
}

__global__ __launch_bounds__(1024) void excl_scan(const int* __restrict__ in, int* __restrict__ out, int n)
{
    __shared__ int wsum[16];
    __shared__ int carry;
    const int tid = threadIdx.x, lane = tid & 63, wv = tid >> 6;
    if (tid == 0) carry = 0;
    __syncthreads();
    for (int base = 0; base < n; base += 1024) {
        int i = base + tid;
        int v = (i < n) ? in[i] : 0;
        int acc = v;
#pragma unroll
        for (int off = 1; off < 64; off <<= 1) {
            int t = __shfl_up(acc, off);
            if (lane >= off) acc += t;
        }
        if (lane == 63) wsum[wv] = acc;
        __syncthreads();
        if (wv == 0 && lane < 16) {
            int s = wsum[lane];
            int a2 = s;
#pragma unroll
            for (int off = 1; off < 16; off <<= 1) {
                int t = __shfl_up(a2, off);
                if (lane >= off) a2 += t;
            }
            wsum[lane] = a2 - s;  // exclusive offset of wave
        }
        __syncthreads();
        int cprev = carry;
        if (i < n) out[i] = cprev + wsum[wv] + acc - v;
        __syncthreads();
        if (tid == 1023) carry = cprev + wsum[15] + acc;
        __syncthreads();
    }
}

__global__ void scatter_edges(const int* __restrict__ src, const int* __restrict__ dst, int E,
                              const int* __restrict__ soff, int* __restrict__ cur,
                              int* __restrict__ ss, int* __restrict__ sd)
{
    int e = blockIdx.x * 256 + threadIdx.x;
    if (e >= E) return;
    int s = src[e];
    int pos = soff[s] + atomicAdd(&cur[s], 1);
    ss[pos] = s;
    sd[pos] = dst[e];
}

// ---------------- per-edge softmax (with 1/(deg_dst+1) folded), fp16 store ----------------
__global__ __launch_bounds__(256) void q_kernel(
    const int* __restrict__ ss, const int* __restrict__ sd, int E,
    const float* __restrict__ xu, const float* __restrict__ cvec,
    const int* __restrict__ indeg, _Float16* __restrict__ Q)
{
    int e = blockIdx.x * 256 + threadIdx.x;
    if (e >= E) return;
    int s = ss[e], d = sd[e];
    float t[NH];
    float m = -1e30f;
#pragma unroll
    for (int h = 0; h < NH; ++h) {
        t[h] = xu[(size_t)s * NH + h] - xu[(size_t)d * NH + h] + cvec[h];
        m = fmaxf(m, t[h]);
    }
    float den = 0.f;
#pragma unroll
    for (int h = 0; h < NH; ++h) { t[h] = __expf(t[h] - m); den += t[h]; }
    float sc = 1.f / (den * (float)(indeg[d] + 1));
#pragma unroll
    for (int h = 0; h < NH; ++h) Q[(size_t)e * NH + h] = (_Float16)(t[h] * sc);
}

// ---------------- per-edge gather+FMA+atomic aggregate (src-sorted) ----------------
template <int OUT>
__global__ __launch_bounds__(256) void feast_edge3(
    const int* __restrict__ ss, const int* __restrict__ sd, int E,
    const _Float16* __restrict__ Q, const float* __restrict__ xw,
    float* __restrict__ agg)
{
    const int G = OUT / 4;
    size_t tid = (size_t)blockIdx.x * 256 + threadIdx.x;
    int e = (int)(tid / G);
    int o = (int)(tid % G);
    if (e >= E) return;
    int s = ss[e], d = sd[e];
    const f32x4* xws = (const f32x4*)(xw + (size_t)s * (NH * OUT)) + o;
    f32x4 acc = {0.f, 0.f, 0.f, 0.f};
#pragma unroll
    for (int h = 0; h < NH; ++h) {
        float qh = (float)Q[(size_t)e * NH + h];
        acc += qh * xws[h * G];
    }
    float* ap = agg + (size_t)d * OUT + o * 4;
    unsafeAtomicAdd(ap + 0, acc[0]);
    unsafeAtomicAdd(ap + 1, acc[1]);
    unsafeAtomicAdd(ap + 2, acc[2]);
    unsafeAtomicAdd(ap + 3, acc[3]);
}

// ---------------- self-loop + mean + bias + (leaky relu), float4, strided output ----------------
template <int OUT>
__global__ __launch_bounds__(256) void feast_fin3(
    const float* __restrict__ agg, const float* __restrict__ xw,
    const float* __restrict__ cvec, const float* __restrict__ bias,
    const int* __restrict__ indeg, float* __restrict__ outp,
    int n, int ldo, int col0, int act)
{
    const int G = OUT / 4;
    size_t tid = (size_t)blockIdx.x * 256 + threadIdx.x;
    int i = (int)(tid / G);
    int o = (int)(tid % G);
    if (i >= n) return;
    float t[NH];
    float m = -1e30f;
#pragma unroll
    for (int h = 0; h < NH; ++h) { t[h] = cvec[h]; m = fmaxf(m, t[h]); }
    float den = 0.f;
#pragma unroll
    for (int h = 0; h < NH; ++h) { t[h] = __expf(t[h] - m); den += t[h]; }
    float sc = 1.f / (den * (float)(indeg[i] + 1));
    const f32x4* xws = (const f32x4*)(xw + (size_t)i * (NH * OUT)) + o;
    f32x4 msg = {0.f, 0.f, 0.f, 0.f};
#pragma unroll
    for (int h = 0; h < NH; ++h) msg += t[h] * xws[h * G];
    f32x4 a4 = *((const f32x4*)(agg + (size_t)i * OUT) + o);
    f32x4 v = a4 + msg * sc;
#pragma unroll
    for (int j = 0; j < 4; ++j) {
        float w = v[j] + bias[o * 4 + j];
        if (act) w = w > 0.f ? w : 0.1f * w;
        v[j] = w;
    }
    *(f32x4*)(outp + (size_t)i * ldo + col0 + o * 4) = v;
}

// ---------------- pooling / unpooling ----------------
__global__ void pool_scatter(const float* __restrict__ xin, int ldx, const int* __restrict__ clust,
                             float* __restrict__ pooled, int C, int n)
{
    size_t tid = (size_t)blockIdx.x * 256 + threadIdx.x;
    int i = (int)(tid / C), c = (int)(tid % C);
    if (i >= n) return;
    atomicAdd(&pooled[(size_t)clust[i] * C + c], xin[(size_t)i * ldx + c]);
}

__global__ void pool_div(float* __restrict__ pooled, const int* __restrict__ pcnt, int C, int m)
{
    size_t tid = (size_t)blockIdx.x * 256 + threadIdx.x;
    int j = (int)(tid / C);
    if (j >= m) return;
    pooled[tid] /= fmaxf((float)pcnt[j], 1.f);
}

__global__ void gather_rows(const float* __restrict__ xin, int ldx, const int* __restrict__ idx,
                            float* __restrict__ outp, int C, int n)
{
    size_t tid = (size_t)blockIdx.x * 256 + threadIdx.x;
    int i = (int)(tid / C), c = (int)(tid % C);
    if (i >= n) return;
    outp[tid] = xin[(size_t)idx[i] * ldx + c];
}

// ---------------- fc1 weight -> fp16 transposed [1024][32] ----------------
__global__ void w1_to_f16t(const float* __restrict__ w1, _Float16* __restrict__ w1t)
{
    int i = blockIdx.x * 256 + threadIdx.x;
    if (i >= 32 * 1024) return;
    int n = i >> 5, k = i & 31;
    w1t[i] = (_Float16)w1[k * 1024 + n];
}

// ---------------- fused FC head via f16 MFMA: lrelu(y@W1+b1)@W2+b2, row-normalize ----------------
__global__ __launch_bounds__(256) void fc_head2(
    const float* __restrict__ yin, const _Float16* __restrict__ w1t,
    const float* __restrict__ b1, const float* __restrict__ w2,
    const float* __restrict__ b2, float* __restrict__ outp, int n)
{
    const int lane = threadIdx.x & 63, wv = threadIdx.x >> 6;
    const int g = lane >> 4, r16 = lane & 15;
    const int node0 = blockIdx.x * 64 + wv * 16;

    // A fragment: 16 nodes x 32 k  (row = lane%16, k = (lane>>4)*8 + j)
    f16x8 afrag;
    int anode = node0 + r16;
    if (anode < n) {
        const float* yr = yin + (size_t)anode * 32 + g * 8;
#pragma unroll
        for (int j = 0; j < 8; ++j) afrag[j] = (_Float16)yr[j];
    } else {
#pragma unroll
        for (int j = 0; j < 8; ++j) afrag[j] = (_Float16)0.f;
    }

    float o0[4] = {0.f, 0.f, 0.f, 0.f};
    float o1[4] = {0.f, 0.f, 0.f, 0.f};
    float o2[4] = {0.f, 0.f, 0.f, 0.f};
    const f32x4 zero4 = {0.f, 0.f, 0.f, 0.f};

#pragma unroll 2
    for (int t = 0; t < 64; ++t) {
        // B fragment: w1t[n=t*16+(lane%16)][k=(lane>>4)*8 + 0..7], contiguous 16B
        const f16x8 bfrag = *(const f16x8*)(w1t + ((size_t)(t * 16 + r16)) * 32 + g * 8);
        f32x4 d = __builtin_amdgcn_mfma_f32_16x16x32_f16(afrag, bfrag, zero4, 0, 0, 0);
        int kh = t * 16 + r16;
        float b1v = b1[kh];
        float w20 = w2[kh * 3], w21 = w2[kh * 3 + 1], w22 = w2[kh * 3 + 2];
#pragma unroll
        for (int r = 0; r < 4; ++r) {
            float h = d[r] + b1v;
            h = h > 0.f ? h : 0.1f * h;
            o0[r] += h * w20;
            o1[r] += h * w21;
            o2[r] += h * w22;
        }
    }
    // reduce across the 16 lanes that share the same 4 node-rows
#pragma unroll
    for (int r = 0; r < 4; ++r) {
#pragma unroll
        for (int off = 1; off < 16; off <<= 1) {
            o0[r] += __shfl_xor(o0[r], off);
            o1[r] += __shfl_xor(o1[r], off);
            o2[r] += __shfl_xor(o2[r], off);
        }
    }
    if (r16 == 0) {
#pragma unroll
        for (int r = 0; r < 4; ++r) {
            int node = node0 + g * 4 + r;
            if (node >= n) continue;
            float v0 = o0[r] + b2[0];
            float v1 = o1[r] + b2[1];
            float v2 = o2[r] + b2[2];
            float nr = fmaxf(sqrtf(v0 * v0 + v1 * v1 + v2 * v2), 1e-12f);
            outp[(size_t)node * 3 + 0] = v0 / nr;
            outp[(size_t)node * 3 + 1] = v1 / nr;
            outp[(size_t)node * 3 + 2] = v2 / nr;
        }
    }
}

// ---------------- dispatch helpers ----------------
static void launch_edge(int outC, const int* ss, const int* sd, int E,
                        const _Float16* Q, const float* xw, float* agg, hipStream_t stream)
{
    dim3 g(ceil_div((size_t)E * (outC / 4), 256));
    if (outC == 32)       feast_edge3<32><<<g, 256, 0, stream>>>(ss, sd, E, Q, xw, agg);
    else if (outC == 64)  feast_edge3<64><<<g, 256, 0, stream>>>(ss, sd, E, Q, xw, agg);
    else                  feast_edge3<128><<<g, 256, 0, stream>>>(ss, sd, E, Q, xw, agg);
}

static void launch_fin(int outC, const float* agg, const float* xw, const float* cvec,
                       const float* bias, const int* indeg, float* outp,
                       int n, int ldo, int col0, int act, hipStream_t stream)
{
    dim3 g(ceil_div((size_t)n * (outC / 4), 256));
    if (outC == 32)       feast_fin3<32><<<g, 256, 0, stream>>>(agg, xw, cvec, bias, indeg, outp, n, ldo, col0, act);
    else if (outC == 64)  feast_fin3<64><<<g, 256, 0, stream>>>(agg, xw, cvec, bias, indeg, outp, n, ldo, col0, act);
    else                  feast_fin3<128><<<g, 256, 0, stream>>>(agg, xw, cvec, bias, indeg, outp, n, ldo, col0, act);
}

extern "C" void kernel_launch(void* const* d_in, const int* in_sizes, int n_in,
                              void* d_out, int out_size, void* d_ws, size_t ws_size,
                              hipStream_t stream)
{
    const float* x      = (const float*)d_in[0];
    const int*   ei1    = (const int*)d_in[1];
    const int*   ei2    = (const int*)d_in[2];
    const int*   ei3    = (const int*)d_in[3];
    const int*   clust2 = (const int*)d_in[4];
    const int*   clust3 = (const int*)d_in[5];
    const float* lp[8][4];
    for (int i = 0; i < 8; ++i)
        for (int j = 0; j < 4; ++j)
            lp[i][j] = (const float*)d_in[6 + i * 4 + j];  // l1..l4,r1..r4 x {u,c,w,b}
    const float* fc1_w = (const float*)d_in[38];
    const float* fc1_b = (const float*)d_in[39];
    const float* fc2_w = (const float*)d_in[40];
    const float* fc2_b = (const float*)d_in[41];
    float* out = (float*)d_out;

    // ---- workspace layout (~220 MB) ----
    char* ws = (char*)d_ws;
    size_t off = 0;
    auto alloc = [&](size_t b) { size_t p = off; off += (b + 255) & ~(size_t)255; return p; };
    float* XW    = (float*)(ws + alloc((size_t)cN1 * NH * 32 * 4));  // 115.2 MB (max xw)
    float* AGG   = (float*)(ws + alloc((size_t)cN1 * 32 * 4));       // 12.8 MB
    float* GATH  = (float*)(ws + alloc((size_t)cN1 * 64 * 4));       // 25.6 MB (pool/unpool scratch; Q alias; YB alias)
    float* X1CAT = (float*)(ws + alloc((size_t)cN1 * 64 * 4));       // 25.6 MB
    float* X2CAT = (float*)(ws + alloc((size_t)cN2 * 128 * 4));      // 12.8 MB
    float* X2B   = (float*)(ws + alloc((size_t)cN2 * 64 * 4));       // 6.4 MB
    float* X3    = (float*)(ws + alloc((size_t)cN3 * 128 * 4));      // 3.2 MB
    float* XU    = (float*)(ws + alloc((size_t)cN1 * NH * 4));       // 3.6 MB
    int* SS1 = (int*)(ws + alloc((size_t)cE1 * 4));
    int* SD1 = (int*)(ws + alloc((size_t)cE1 * 4));
    int* SS2 = (int*)(ws + alloc((size_t)cE2 * 4));
    int* SD2 = (int*)(ws + alloc((size_t)cE2 * 4));
    int* SS3 = (int*)(ws + alloc((size_t)cE3 * 4));
    int* SD3 = (int*)(ws + alloc((size_t)cE3 * 4));
    int* SOFF1 = (int*)(ws + alloc((size_t)cN1 * 4));
    int* SOFF2 = (int*)(ws + alloc((size_t)cN2 * 4));
    int* SOFF3 = (int*)(ws + alloc((size_t)cN3 * 4));
    int* OCNT1 = (int*)(ws + alloc((size_t)cN1 * 4));
    int* OCNT2 = (int*)(ws + alloc((size_t)cN2 * 4));
    int* OCNT3 = (int*)(ws + alloc((size_t)cN3 * 4));
    int* CUR   = (int*)(ws + alloc((size_t)cN1 * 4));
    int* CNT1 = (int*)(ws + alloc((size_t)cN1 * 4));
    int* CNT2 = (int*)(ws + alloc((size_t)cN2 * 4));
    int* CNT3 = (int*)(ws + alloc((size_t)cN3 * 4));
    int* PC2  = (int*)(ws + alloc((size_t)cN2 * 4));
    int* PC3  = (int*)(ws + alloc((size_t)cN3 * 4));
    _Float16* W1T = (_Float16*)(ws + alloc((size_t)32 * 1024 * 2));
    _Float16* Q = (_Float16*)GATH;  // fp16 q, alias (E1*9*2 = 21.6 MB <= 25.6 MB)
    float* YB = GATH;               // r4 output aliases scratch (free by then)

    // ---- degrees (dst) + src-sort of all three edge lists ----
    hipMemsetAsync(CNT1, 0, (size_t)cN1 * 4, stream);
    hipMemsetAsync(CNT2, 0, (size_t)cN2 * 4, stream);
    hipMemsetAsync(CNT3, 0, (size_t)cN3 * 4, stream);
    hipMemsetAsync(OCNT1, 0, (size_t)cN1 * 4, stream);
    hipMemsetAsync(OCNT2, 0, (size_t)cN2 * 4, stream);
    hipMemsetAsync(OCNT3, 0, (size_t)cN3 * 4, stream);
    count_idx<<<ceil_div(cE1, 256), 256, 0, stream>>>(ei1 + cE1, cE1, CNT1);
    count_idx<<<ceil_div(cE2, 256), 256, 0, stream>>>(ei2 + cE2, cE2, CNT2);
    count_idx<<<ceil_div(cE3, 256), 256, 0, stream>>>(ei3 + cE3, cE3, CNT3);
    count_idx<<<ceil_div(cE1, 256), 256, 0, stream>>>(ei1, cE1, OCNT1);
    count_idx<<<ceil_div(cE2, 256), 256, 0, stream>>>(ei2, cE2, OCNT2);
    count_idx<<<ceil_div(cE3, 256), 256, 0, stream>>>(ei3, cE3, OCNT3);
    excl_scan<<<1, 1024, 0, stream>>>(OCNT1, SOFF1, cN1);
    excl_scan<<<1, 1024, 0, stream>>>(OCNT2, SOFF2, cN2);
    excl_scan<<<1, 1024, 0, stream>>>(OCNT3, SOFF3, cN3);
    hipMemsetAsync(CUR, 0, (size_t)cN1 * 4, stream);
    scatter_edges<<<ceil_div(cE1, 256), 256, 0, stream>>>(ei1, ei1 + cE1, cE1, SOFF1, CUR, SS1, SD1);
    hipMemsetAsync(CUR, 0, (size_t)cN2 * 4, stream);
    scatter_edges<<<ceil_div(cE2, 256), 256, 0, stream>>>(ei2, ei2 + cE2, cE2, SOFF2, CUR, SS2, SD2);
    hipMemsetAsync(CUR, 0, (size_t)cN3 * 4, stream);
    scatter_edges<<<ceil_div(cE3, 256), 256, 0, stream>>>(ei3, ei3 + cE3, cE3, SOFF3, CUR, SS3, SD3);

    // fc1 weights -> fp16 transposed
    w1_to_f16t<<<ceil_div(32 * 1024, 256), 256, 0, stream>>>(fc1_w, W1T);

    auto feast = [&](const float* xin, int ldx, int n, int cin, int outC,
                     const int* ss, const int* sd, int E, const int* indeg,
                     const float* const* L, float* dstp, int ldo, int col0, int act) {
        // xu = xin @ u  [n, 9]
        gemm_f32<<<dim3(1, ceil_div(n, 64)), 256, 0, stream>>>(xin, ldx, L[0], NH, XU, NH, n, NH, cin);
        // xw = xin @ W  [n, 9*outC]
        int NC = NH * outC;
        gemm_f32<<<dim3(ceil_div(NC, 64), ceil_div(n, 64)), 256, 0, stream>>>(xin, ldx, L[2], NC, XW, NC, n, NC, cin);
        // per-edge softmax (after gemms: Q may alias the feast input scratch)
        q_kernel<<<ceil_div(E, 256), 256, 0, stream>>>(ss, sd, E, XU, L[1], indeg, Q);
        hipMemsetAsync(AGG, 0, (size_t)n * outC * 4, stream);
        launch_edge(outC, ss, sd, E, Q, XW, AGG, stream);
        launch_fin(outC, AGG, XW, L[1], L[3], indeg, dstp, n, ldo, col0, act, stream);
    };

    // l1: [N1,6] -> [N1,32] into X1CAT[:, 0:32]
    feast(x, 6, cN1, 6, 32, SS1, SD1, cE1, CNT1, lp[0], X1CAT, 64, 0, 1);

    // pool -> [N2,32] in GATH
    hipMemsetAsync(PC2, 0, (size_t)cN2 * 4, stream);
    hipMemsetAsync(GATH, 0, (size_t)cN2 * 32 * 4, stream);
    count_idx<<<ceil_div(cN1, 256), 256, 0, stream>>>(clust2, cN1, PC2);
    pool_scatter<<<ceil_div((size_t)cN1 * 32, 256), 256, 0, stream>>>(X1CAT, 64, clust2, GATH, 32, cN1);
    pool_div<<<ceil_div((size_t)cN2 * 32, 256), 256, 0, stream>>>(GATH, PC2, 32, cN2);

    // l2: [N2,32] -> [N2,64] into X2CAT[:, 0:64]
    feast(GATH, 32, cN2, 32, 64, SS2, SD2, cE2, CNT2, lp[1], X2CAT, 128, 0, 1);

    // pool -> [N3,64] in GATH
    hipMemsetAsync(PC3, 0, (size_t)cN3 * 4, stream);
    hipMemsetAsync(GATH, 0, (size_t)cN3 * 64 * 4, stream);
    count_idx<<<ceil_div(cN2, 256), 256, 0, stream>>>(clust3, cN2, PC3);
    pool_scatter<<<ceil_div((size_t)cN2 * 64, 256), 256, 0, stream>>>(X2CAT, 128, clust3, GATH, 64, cN2);
    pool_div<<<ceil_div((size_t)cN3 * 64, 256), 256, 0, stream>>>(GATH, PC3, 64, cN3);

    // l3: [N3,64] -> [N3,128] into X3
    feast(GATH, 64, cN3, 64, 128, SS3, SD3, cE3, CNT3, lp[2], X3, 128, 0, 1);
    // l4: [N3,128] -> [N3,128] in-place
    feast(X3, 128, cN3, 128, 128, SS3, SD3, cE3, CNT3, lp[3], X3, 128, 0, 1);

    // r1: unpool x3 -> [N2,128], feast -> X2CAT[:, 64:128] (no act)
    gather_rows<<<ceil_div((size_t)cN2 * 128, 256), 256, 0, stream>>>(X3, 128, clust3, GATH, 128, cN2);
    feast(GATH, 128, cN2, 128, 64, SS2, SD2, cE2, CNT2, lp[4], X2CAT, 128, 64, 0);

    // r2: [N2,128] -> [N2,64] into X2B
    feast(X2CAT, 128, cN2, 128, 64, SS2, SD2, cE2, CNT2, lp[5], X2B, 64, 0, 1);

    // r3: unpool x2 -> [N1,64], feast -> X1CAT[:, 32:64] (no act)
    gather_rows<<<ceil_div((size_t)cN1 * 64, 256), 256, 0, stream>>>(X2B, 64, clust2, GATH, 64, cN1);
    feast(GATH, 64, cN1, 64, 32, SS1, SD1, cE1, CNT1, lp[6], X1CAT, 64, 32, 0);

    // r4: [N1,64] -> [N1,32] into YB
    feast(X1CAT, 64, cN1, 64, 32, SS1, SD1, cE1, CNT1, lp[7], YB, 32, 0, 1);

    // fused FC head + normalize (f16 MFMA)
    fc_head2<<<ceil_div(cN1, 64), 256, 0, stream>>>(YB, W1T, fc1_b, fc2_w, fc2_b, out, cN1);

    (void)in_sizes; (void)n_in; (void)out_size; (void)ws_size;
}

// Round 4
// 2161.577 us; speedup vs baseline: 1.8510x; 1.8510x over previous
//
#include <hip/hip_runtime.h>
#include <cstddef>
#include <cstdint>

#define NH 9

typedef _Float16 f16x8 __attribute__((ext_vector_type(8)));
typedef float f32x4 __attribute__((ext_vector_type(4)));

static const int cN1 = 100000, cN2 = 25000, cN3 = 6250;
static const int cE1 = 1200000, cE2 = 300000, cE3 = 75000;

static inline unsigned ceil_div(size_t a, size_t b) { return (unsigned)((a + b - 1) / b); }

// ---------------- generic fp32 GEMM: C[M,N] = A[M,K](lda) @ B[K,N](ldb) ----------------
__global__ __launch_bounds__(256) void gemm_f32(
    const float* __restrict__ A, int lda,
    const float* __restrict__ B, int ldb,
    float* __restrict__ C, int ldc,
    int M, int N, int K)
{
    const int BM = 64, BN = 64, BK = 16;
    __shared__ float As[BK][BM + 1];
    __shared__ float Bs[BK][BN + 1];
    const int tid = threadIdx.x;
    const int tx = tid & 15, ty = tid >> 4;
    const int row0 = blockIdx.y * BM, col0 = blockIdx.x * BN;
    float acc[4][4] = {};
    for (int k0 = 0; k0 < K; k0 += BK) {
        for (int l = tid; l < BM * BK; l += 256) {
            int r = l >> 4, c = l & 15;
            float v = 0.f;
            if (row0 + r < M && k0 + c < K) v = A[(size_t)(row0 + r) * lda + (k0 + c)];
            As[c][r] = v;
        }
        for (int l = tid; l < BK * BN; l += 256) {
            int r = l >> 6, c = l & 63;
            float v = 0.f;
            if (k0 + r < K && col0 + c < N) v = B[(size_t)(k0 + r) * ldb + (col0 + c)];
            Bs[r][c] = v;
        }
        __syncthreads();
#pragma unroll
        for (int kk = 0; kk < BK; ++kk) {
            float a[4], b[4];
#pragma unroll
            for (int i = 0; i < 4; ++i) a[i] = As[kk][ty * 4 + i];
#pragma unroll
            for (int j = 0; j < 4; ++j) b[j] = Bs[kk][tx * 4 + j];
#pragma unroll
            for (int i = 0; i < 4; ++i)
#pragma unroll
                for (int j = 0; j < 4; ++j) acc[i][j] += a[i] * b[j];
        }
        __syncthreads();
    }
#pragma unroll
    for (int i = 0; i < 4; ++i) {
        int r = row0 + ty * 4 + i;
        if (r >= M) break;
#pragma unroll
        for (int j = 0; j < 4; ++j) {
            int c = col0 + tx * 4 + j;
            if (c < N) C[(size_t)r * ldc + c] = acc[i][j];
        }
    }
}

// ---------------- sorting: count / scan / scatter ----------------
__global__ void count_idx(const int* __restrict__ idx, int n, int* __restrict__ cnt)
{
    int i = blockIdx.x * 256 + threadIdx.x;
    if (i < n) atomicAdd(&cnt[idx[i]], 1);
}

__global__ __launch_bounds__(1024) void excl_scan(const int* __restrict__ in, int* __restrict__ out, int n)
{
    __shared__ int wsum[16];
    __shared__ int carry;
    const int tid = threadIdx.x, lane = tid & 63, wv = tid >> 6;
    if (tid == 0) carry = 0;
    __syncthreads();
    for (int base = 0; base < n; base += 1024) {
        int i = base + tid;
        int v = (i < n) ? in[i] : 0;
        int acc = v;
#pragma unroll
        for (int off = 1; off < 64; off <<= 1) {
            int t = __shfl_up(acc, off);
            if (lane >= off) acc += t;
        }
        if (lane == 63) wsum[wv] = acc;
        __syncthreads();
        if (wv == 0 && lane < 16) {
            int s = wsum[lane];
            int a2 = s;
#pragma unroll
            for (int off = 1; off < 16; off <<= 1) {
                int t = __shfl_up(a2, off);
                if (lane >= off) a2 += t;
            }
            wsum[lane] = a2 - s;  // exclusive offset of wave
        }
        __syncthreads();
        int cprev = carry;
        if (i < n) out[i] = cprev + wsum[wv] + acc - v;
        __syncthreads();
        if (tid == 1023) carry = cprev + wsum[15] + acc;
        __syncthreads();
    }
}

__global__ void scatter_edges(const int* __restrict__ src, const int* __restrict__ dst, int E,
                              const int* __restrict__ soff, int* __restrict__ cur,
                              int* __restrict__ ss, int* __restrict__ sd)
{
    int e = blockIdx.x * 256 + threadIdx.x;
    if (e >= E) return;
    int s = src[e];
    int pos = soff[s] + atomicAdd(&cur[s], 1);
    ss[pos] = s;
    sd[pos] = dst[e];
}

// ---------------- per-edge softmax (with 1/(deg_dst+1) folded), fp16 store ----------------
__global__ __launch_bounds__(256) void q_kernel(
    const int* __restrict__ ss, const int* __restrict__ sd, int E,
    const float* __restrict__ xu, const float* __restrict__ cvec,
    const int* __restrict__ indeg, _Float16* __restrict__ Q)
{
    int e = blockIdx.x * 256 + threadIdx.x;
    if (e >= E) return;
    int s = ss[e], d = sd[e];
    float t[NH];
    float m = -1e30f;
#pragma unroll
    for (int h = 0; h < NH; ++h) {
        t[h] = xu[(size_t)s * NH + h] - xu[(size_t)d * NH + h] + cvec[h];
        m = fmaxf(m, t[h]);
    }
    float den = 0.f;
#pragma unroll
    for (int h = 0; h < NH; ++h) { t[h] = __expf(t[h] - m); den += t[h]; }
    float sc = 1.f / (den * (float)(indeg[d] + 1));
#pragma unroll
    for (int h = 0; h < NH; ++h) Q[(size_t)e * NH + h] = (_Float16)(t[h] * sc);
}

// ---------------- per-edge gather+FMA+atomic aggregate ----------------
// One lane per (edge, channel): a wave's atomics cover complete contiguous agg
// rows (full 128B-line RMW at L2, 4B/atomic effective write) -- the 8-lane/row
// f32x4 variant caused 16B write granules (600MB vs 150MB, 2x slower).
template <int OUT>
__global__ __launch_bounds__(256) void feast_edge4(
    const int* __restrict__ ss, const int* __restrict__ sd, int E,
    const _Float16* __restrict__ Q, const float* __restrict__ xw,
    float* __restrict__ agg)
{
    size_t tid = (size_t)blockIdx.x * 256 + threadIdx.x;
    int e = (int)(tid / OUT);
    int o = (int)(tid % OUT);
    if (e >= E) return;
    int s = ss[e], d = sd[e];
    const _Float16* qe = Q + (size_t)e * NH;
    const float* xws = xw + (size_t)s * (NH * OUT) + o;
    float msg = 0.f;
#pragma unroll
    for (int h = 0; h < NH; ++h) msg += (float)qe[h] * xws[h * OUT];
    unsafeAtomicAdd(&agg[(size_t)d * OUT + o], msg);
}

// ---------------- self-loop + mean + bias + (leaky relu), float4, strided output ----------------
template <int OUT>
__global__ __launch_bounds__(256) void feast_fin3(
    const float* __restrict__ agg, const float* __restrict__ xw,
    const float* __restrict__ cvec, const float* __restrict__ bias,
    const int* __restrict__ indeg, float* __restrict__ outp,
    int n, int ldo, int col0, int act)
{
    const int G = OUT / 4;
    size_t tid = (size_t)blockIdx.x * 256 + threadIdx.x;
    int i = (int)(tid / G);
    int o = (int)(tid % G);
    if (i >= n) return;
    float t[NH];
    float m = -1e30f;
#pragma unroll
    for (int h = 0; h < NH; ++h) { t[h] = cvec[h]; m = fmaxf(m, t[h]); }
    float den = 0.f;
#pragma unroll
    for (int h = 0; h < NH; ++h) { t[h] = __expf(t[h] - m); den += t[h]; }
    float sc = 1.f / (den * (float)(indeg[i] + 1));
    const f32x4* xws = (const f32x4*)(xw + (size_t)i * (NH * OUT)) + o;
    f32x4 msg = {0.f, 0.f, 0.f, 0.f};
#pragma unroll
    for (int h = 0; h < NH; ++h) msg += t[h] * xws[h * G];
    f32x4 a4 = *((const f32x4*)(agg + (size_t)i * OUT) + o);
    f32x4 v = a4 + msg * sc;
#pragma unroll
    for (int j = 0; j < 4; ++j) {
        float w = v[j] + bias[o * 4 + j];
        if (act) w = w > 0.f ? w : 0.1f * w;
        v[j] = w;
    }
    *(f32x4*)(outp + (size_t)i * ldo + col0 + o * 4) = v;
}

// ---------------- pooling / unpooling ----------------
__global__ void pool_scatter(const float* __restrict__ xin, int ldx, const int* __restrict__ clust,
                             float* __restrict__ pooled, int C, int n)
{
    size_t tid = (size_t)blockIdx.x * 256 + threadIdx.x;
    int i = (int)(tid / C), c = (int)(tid % C);
    if (i >= n) return;
    atomicAdd(&pooled[(size_t)clust[i] * C + c], xin[(size_t)i * ldx + c]);
}

__global__ void pool_div(float* __restrict__ pooled, const int* __restrict__ pcnt, int C, int m)
{
    size_t tid = (size_t)blockIdx.x * 256 + threadIdx.x;
    int j = (int)(tid / C);
    if (j >= m) return;
    pooled[tid] /= fmaxf((float)pcnt[j], 1.f);
}

__global__ void gather_rows(const float* __restrict__ xin, int ldx, const int* __restrict__ idx,
                            float* __restrict__ outp, int C, int n)
{
    size_t tid = (size_t)blockIdx.x * 256 + threadIdx.x;
    int i = (int)(tid / C), c = (int)(tid % C);
    if (i >= n) return;
    outp[tid] = xin[(size_t)idx[i] * ldx + c];
}

// ---------------- fc1 weight -> fp16 transposed [1024][32] ----------------
__global__ void w1_to_f16t(const float* __restrict__ w1, _Float16* __restrict__ w1t)
{
    int i = blockIdx.x * 256 + threadIdx.x;
    if (i >= 32 * 1024) return;
    int n = i >> 5, k = i & 31;
    w1t[i] = (_Float16)w1[k * 1024 + n];
}

// ---------------- fused FC head via f16 MFMA: lrelu(y@W1+b1)@W2+b2, row-normalize ----------------
__global__ __launch_bounds__(256) void fc_head2(
    const float* __restrict__ yin, const _Float16* __restrict__ w1t,
    const float* __restrict__ b1, const float* __restrict__ w2,
    const float* __restrict__ b2, float* __restrict__ outp, int n)
{
    const int lane = threadIdx.x & 63, wv = threadIdx.x >> 6;
    const int g = lane >> 4, r16 = lane & 15;
    const int node0 = blockIdx.x * 64 + wv * 16;

    // A fragment: 16 nodes x 32 k  (row = lane%16, k = (lane>>4)*8 + j)
    f16x8 afrag;
    int anode = node0 + r16;
    if (anode < n) {
        const float* yr = yin + (size_t)anode * 32 + g * 8;
#pragma unroll
        for (int j = 0; j < 8; ++j) afrag[j] = (_Float16)yr[j];
    } else {
#pragma unroll
        for (int j = 0; j < 8; ++j) afrag[j] = (_Float16)0.f;
    }

    float o0[4] = {0.f, 0.f, 0.f, 0.f};
    float o1[4] = {0.f, 0.f, 0.f, 0.f};
    float o2[4] = {0.f, 0.f, 0.f, 0.f};
    const f32x4 zero4 = {0.f, 0.f, 0.f, 0.f};

#pragma unroll 2
    for (int t = 0; t < 64; ++t) {
        // B fragment: w1t[n=t*16+(lane%16)][k=(lane>>4)*8 + 0..7], contiguous 16B
        const f16x8 bfrag = *(const f16x8*)(w1t + ((size_t)(t * 16 + r16)) * 32 + g * 8);
        f32x4 d = __builtin_amdgcn_mfma_f32_16x16x32_f16(afrag, bfrag, zero4, 0, 0, 0);
        int kh = t * 16 + r16;
        float b1v = b1[kh];
        float w20 = w2[kh * 3], w21 = w2[kh * 3 + 1], w22 = w2[kh * 3 + 2];
#pragma unroll
        for (int r = 0; r < 4; ++r) {
            float h = d[r] + b1v;
            h = h > 0.f ? h : 0.1f * h;
            o0[r] += h * w20;
            o1[r] += h * w21;
            o2[r] += h * w22;
        }
    }
    // reduce across the 16 lanes that share the same 4 node-rows
#pragma unroll
    for (int r = 0; r < 4; ++r) {
#pragma unroll
        for (int off = 1; off < 16; off <<= 1) {
            o0[r] += __shfl_xor(o0[r], off);
            o1[r] += __shfl_xor(o1[r], off);
            o2[r] += __shfl_xor(o2[r], off);
        }
    }
    if (r16 == 0) {
#pragma unroll
        for (int r = 0; r < 4; ++r) {
            int node = node0 + g * 4 + r;
            if (node >= n) continue;
            float v0 = o0[r] + b2[0];
            float v1 = o1[r] + b2[1];
            float v2 = o2[r] + b2[2];
            float nr = fmaxf(sqrtf(v0 * v0 + v1 * v1 + v2 * v2), 1e-12f);
            outp[(size_t)node * 3 + 0] = v0 / nr;
            outp[(size_t)node * 3 + 1] = v1 / nr;
            outp[(size_t)node * 3 + 2] = v2 / nr;
        }
    }
}

// ---------------- dispatch helpers ----------------
static void launch_edge(int outC, const int* ss, const int* sd, int E,
                        const _Float16* Q, const float* xw, float* agg, hipStream_t stream)
{
    dim3 g(ceil_div((size_t)E * outC, 256));
    if (outC == 32)       feast_edge4<32><<<g, 256, 0, stream>>>(ss, sd, E, Q, xw, agg);
    else if (outC == 64)  feast_edge4<64><<<g, 256, 0, stream>>>(ss, sd, E, Q, xw, agg);
    else                  feast_edge4<128><<<g, 256, 0, stream>>>(ss, sd, E, Q, xw, agg);
}

static void launch_fin(int outC, const float* agg, const float* xw, const float* cvec,
                       const float* bias, const int* indeg, float* outp,
                       int n, int ldo, int col0, int act, hipStream_t stream)
{
    dim3 g(ceil_div((size_t)n * (outC / 4), 256));
    if (outC == 32)       feast_fin3<32><<<g, 256, 0, stream>>>(agg, xw, cvec, bias, indeg, outp, n, ldo, col0, act);
    else if (outC == 64)  feast_fin3<64><<<g, 256, 0, stream>>>(agg, xw, cvec, bias, indeg, outp, n, ldo, col0, act);
    else                  feast_fin3<128><<<g, 256, 0, stream>>>(agg, xw, cvec, bias, indeg, outp, n, ldo, col0, act);
}

extern "C" void kernel_launch(void* const* d_in, const int* in_sizes, int n_in,
                              void* d_out, int out_size, void* d_ws, size_t ws_size,
                              hipStream_t stream)
{
    const float* x      = (const float*)d_in[0];
    const int*   ei1    = (const int*)d_in[1];
    const int*   ei2    = (const int*)d_in[2];
    const int*   ei3    = (const int*)d_in[3];
    const int*   clust2 = (const int*)d_in[4];
    const int*   clust3 = (const int*)d_in[5];
    const float* lp[8][4];
    for (int i = 0; i < 8; ++i)
        for (int j = 0; j < 4; ++j)
            lp[i][j] = (const float*)d_in[6 + i * 4 + j];  // l1..l4,r1..r4 x {u,c,w,b}
    const float* fc1_w = (const float*)d_in[38];
    const float* fc1_b = (const float*)d_in[39];
    const float* fc2_w = (const float*)d_in[40];
    const float* fc2_b = (const float*)d_in[41];
    float* out = (float*)d_out;

    // ---- workspace layout (~220 MB) ----
    char* ws = (char*)d_ws;
    size_t off = 0;
    auto alloc = [&](size_t b) { size_t p = off; off += (b + 255) & ~(size_t)255; return p; };
    float* XW    = (float*)(ws + alloc((size_t)cN1 * NH * 32 * 4));  // 115.2 MB (max xw)
    float* AGG   = (float*)(ws + alloc((size_t)cN1 * 32 * 4));       // 12.8 MB
    float* GATH  = (float*)(ws + alloc((size_t)cN1 * 64 * 4));       // 25.6 MB (pool/unpool scratch; Q alias; YB alias)
    float* X1CAT = (float*)(ws + alloc((size_t)cN1 * 64 * 4));       // 25.6 MB
    float* X2CAT = (float*)(ws + alloc((size_t)cN2 * 128 * 4));      // 12.8 MB
    float* X2B   = (float*)(ws + alloc((size_t)cN2 * 64 * 4));       // 6.4 MB
    float* X3    = (float*)(ws + alloc((size_t)cN3 * 128 * 4));      // 3.2 MB
    float* XU    = (float*)(ws + alloc((size_t)cN1 * NH * 4));       // 3.6 MB
    int* SS1 = (int*)(ws + alloc((size_t)cE1 * 4));
    int* SD1 = (int*)(ws + alloc((size_t)cE1 * 4));
    int* SS2 = (int*)(ws + alloc((size_t)cE2 * 4));
    int* SD2 = (int*)(ws + alloc((size_t)cE2 * 4));
    int* SS3 = (int*)(ws + alloc((size_t)cE3 * 4));
    int* SD3 = (int*)(ws + alloc((size_t)cE3 * 4));
    int* SOFF1 = (int*)(ws + alloc((size_t)cN1 * 4));
    int* SOFF2 = (int*)(ws + alloc((size_t)cN2 * 4));
    int* SOFF3 = (int*)(ws + alloc((size_t)cN3 * 4));
    int* OCNT1 = (int*)(ws + alloc((size_t)cN1 * 4));
    int* OCNT2 = (int*)(ws + alloc((size_t)cN2 * 4));
    int* OCNT3 = (int*)(ws + alloc((size_t)cN3 * 4));
    int* CUR   = (int*)(ws + alloc((size_t)cN1 * 4));
    int* CNT1 = (int*)(ws + alloc((size_t)cN1 * 4));
    int* CNT2 = (int*)(ws + alloc((size_t)cN2 * 4));
    int* CNT3 = (int*)(ws + alloc((size_t)cN3 * 4));
    int* PC2  = (int*)(ws + alloc((size_t)cN2 * 4));
    int* PC3  = (int*)(ws + alloc((size_t)cN3 * 4));
    _Float16* W1T = (_Float16*)(ws + alloc((size_t)32 * 1024 * 2));
    _Float16* Q = (_Float16*)GATH;  // fp16 q, alias (E1*9*2 = 21.6 MB <= 25.6 MB)
    float* YB = GATH;               // r4 output aliases scratch (free by then)

    // ---- degrees (dst) + src-sort of all three edge lists ----
    hipMemsetAsync(CNT1, 0, (size_t)cN1 * 4, stream);
    hipMemsetAsync(CNT2, 0, (size_t)cN2 * 4, stream);
    hipMemsetAsync(CNT3, 0, (size_t)cN3 * 4, stream);
    hipMemsetAsync(OCNT1, 0, (size_t)cN1 * 4, stream);
    hipMemsetAsync(OCNT2, 0, (size_t)cN2 * 4, stream);
    hipMemsetAsync(OCNT3, 0, (size_t)cN3 * 4, stream);
    count_idx<<<ceil_div(cE1, 256), 256, 0, stream>>>(ei1 + cE1, cE1, CNT1);
    count_idx<<<ceil_div(cE2, 256), 256, 0, stream>>>(ei2 + cE2, cE2, CNT2);
    count_idx<<<ceil_div(cE3, 256), 256, 0, stream>>>(ei3 + cE3, cE3, CNT3);
    count_idx<<<ceil_div(cE1, 256), 256, 0, stream>>>(ei1, cE1, OCNT1);
    count_idx<<<ceil_div(cE2, 256), 256, 0, stream>>>(ei2, cE2, OCNT2);
    count_idx<<<ceil_div(cE3, 256), 256, 0, stream>>>(ei3, cE3, OCNT3);
    excl_scan<<<1, 1024, 0, stream>>>(OCNT1, SOFF1, cN1);
    excl_scan<<<1, 1024, 0, stream>>>(OCNT2, SOFF2, cN2);
    excl_scan<<<1, 1024, 0, stream>>>(OCNT3, SOFF3, cN3);
    hipMemsetAsync(CUR, 0, (size_t)cN1 * 4, stream);
    scatter_edges<<<ceil_div(cE1, 256), 256, 0, stream>>>(ei1, ei1 + cE1, cE1, SOFF1, CUR, SS1, SD1);
    hipMemsetAsync(CUR, 0, (size_t)cN2 * 4, stream);
    scatter_edges<<<ceil_div(cE2, 256), 256, 0, stream>>>(ei2, ei2 + cE2, cE2, SOFF2, CUR, SS2, SD2);
    hipMemsetAsync(CUR, 0, (size_t)cN3 * 4, stream);
    scatter_edges<<<ceil_div(cE3, 256), 256, 0, stream>>>(ei3, ei3 + cE3, cE3, SOFF3, CUR, SS3, SD3);

    // fc1 weights -> fp16 transposed
    w1_to_f16t<<<ceil_div(32 * 1024, 256), 256, 0, stream>>>(fc1_w, W1T);

    auto feast = [&](const float* xin, int ldx, int n, int cin, int outC,
                     const int* ss, const int* sd, int E, const int* indeg,
                     const float* const* L, float* dstp, int ldo, int col0, int act) {
        // xu = xin @ u  [n, 9]
        gemm_f32<<<dim3(1, ceil_div(n, 64)), 256, 0, stream>>>(xin, ldx, L[0], NH, XU, NH, n, NH, cin);
        // xw = xin @ W  [n, 9*outC]
        int NC = NH * outC;
        gemm_f32<<<dim3(ceil_div(NC, 64), ceil_div(n, 64)), 256, 0, stream>>>(xin, ldx, L[2], NC, XW, NC, n, NC, cin);
        // per-edge softmax (after gemms: Q may alias the feast input scratch)
        q_kernel<<<ceil_div(E, 256), 256, 0, stream>>>(ss, sd, E, XU, L[1], indeg, Q);
        hipMemsetAsync(AGG, 0, (size_t)n * outC * 4, stream);
        launch_edge(outC, ss, sd, E, Q, XW, AGG, stream);
        launch_fin(outC, AGG, XW, L[1], L[3], indeg, dstp, n, ldo, col0, act, stream);
    };

    // l1: [N1,6] -> [N1,32] into X1CAT[:, 0:32]
    feast(x, 6, cN1, 6, 32, SS1, SD1, cE1, CNT1, lp[0], X1CAT, 64, 0, 1);

    // pool -> [N2,32] in GATH
    hipMemsetAsync(PC2, 0, (size_t)cN2 * 4, stream);
    hipMemsetAsync(GATH, 0, (size_t)cN2 * 32 * 4, stream);
    count_idx<<<ceil_div(cN1, 256), 256, 0, stream>>>(clust2, cN1, PC2);
    pool_scatter<<<ceil_div((size_t)cN1 * 32, 256), 256, 0, stream>>>(X1CAT, 64, clust2, GATH, 32, cN1);
    pool_div<<<ceil_div((size_t)cN2 * 32, 256), 256, 0, stream>>>(GATH, PC2, 32, cN2);

    // l2: [N2,32] -> [N2,64] into X2CAT[:, 0:64]
    feast(GATH, 32, cN2, 32, 64, SS2, SD2, cE2, CNT2, lp[1], X2CAT, 128, 0, 1);

    // pool -> [N3,64] in GATH
    hipMemsetAsync(PC3, 0, (size_t)cN3 * 4, stream);
    hipMemsetAsync(GATH, 0, (size_t)cN3 * 64 * 4, stream);
    count_idx<<<ceil_div(cN2, 256), 256, 0, stream>>>(clust3, cN2, PC3);
    pool_scatter<<<ceil_div((size_t)cN2 * 64, 256), 256, 0, stream>>>(X2CAT, 128, clust3, GATH, 64, cN2);
    pool_div<<<ceil_div((size_t)cN3 * 64, 256), 256, 0, stream>>>(GATH, PC3, 64, cN3);

    // l3: [N3,64] -> [N3,128] into X3
    feast(GATH, 64, cN3, 64, 128, SS3, SD3, cE3, CNT3, lp[2], X3, 128, 0, 1);
    // l4: [N3,128] -> [N3,128] in-place
    feast(X3, 128, cN3, 128, 128, SS3, SD3, cE3, CNT3, lp[3], X3, 128, 0, 1);

    // r1: unpool x3 -> [N2,128], feast -> X2CAT[:, 64:128] (no act)
    gather_rows<<<ceil_div((size_t)cN2 * 128, 256), 256, 0, stream>>>(X3, 128, clust3, GATH, 128, cN2);
    feast(GATH, 128, cN2, 128, 64, SS2, SD2, cE2, CNT2, lp[4], X2CAT, 128, 64, 0);

    // r2: [N2,128] -> [N2,64] into X2B
    feast(X2CAT, 128, cN2, 128, 64, SS2, SD2, cE2, CNT2, lp[5], X2B, 64, 0, 1);

    // r3: unpool x2 -> [N1,64], feast -> X1CAT[:, 32:64] (no act)
    gather_rows<<<ceil_div((size_t)cN1 * 64, 256), 256, 0, stream>>>(X2B, 64, clust2, GATH, 64, cN1);
    feast(GATH, 64, cN1, 64, 32, SS1, SD1, cE1, CNT1, lp[6], X1CAT, 64, 32, 0);

    // r4: [N1,64] -> [N1,32] into YB
    feast(X1CAT, 64, cN1, 64, 32, SS1, SD1, cE1, CNT1, lp[7], YB, 32, 0, 1);

    // fused FC head + normalize (f16 MFMA)
    fc_head2<<<ceil_div(cN1, 64), 256, 0, stream>>>(YB, W1T, fc1_b, fc2_w, fc2_b, out, cN1);

    (void)in_sizes; (void)n_in; (void)out_size; (void)ws_size;
}

// Round 5
// 1448.150 us; speedup vs baseline: 2.7629x; 1.4926x over previous
//
#include <hip/hip_runtime.h>
#include <cstddef>
#include <cstdint>

#define NH 9

typedef _Float16 f16x8 __attribute__((ext_vector_type(8)));
typedef float f32x4 __attribute__((ext_vector_type(4)));

static const int cN1 = 100000, cN2 = 25000, cN3 = 6250;
static const int cE1 = 1200000, cE2 = 300000, cE3 = 75000;

static inline unsigned ceil_div(size_t a, size_t b) { return (unsigned)((a + b - 1) / b); }

// ---------------- f16 MFMA GEMM: C[M,N] = A[M,K](f32,lda) @ B[K,N](f32,ldb) ----------------
// Inputs converted f32->f16 during LDS staging; acc fp32; C stored as CT (f16 or f32).
// Fragment layout: A row=lane&15, k=(lane>>4)*8+j ; B col=lane&15, same k ;
// D col=lane&15, row=(lane>>4)*4+reg  (verified numerically via fc_head2, rounds 3-4).
template <typename CT>
__global__ __launch_bounds__(256) void gemm_mfma(
    const float* __restrict__ A, int lda,
    const float* __restrict__ B, int ldb,
    CT* __restrict__ C, int ldc, int M, int N, int K)
{
    const int BM = 64, BN = 64, BK = 32, LK = 40;  // LK pad keeps 16B align, spreads banks
    __shared__ _Float16 As[BM][LK];
    __shared__ _Float16 Bs[BN][LK];  // stored transposed: Bs[n][k]
    const int tid = threadIdx.x;
    const int row0 = blockIdx.y * BM, col0 = blockIdx.x * BN;
    const int lane = tid & 63, wv = tid >> 6;
    const int g = lane >> 4, r16 = lane & 15;
    const int wr = wv >> 1, wc = wv & 1;  // 2x2 wave grid, 32x32 per wave
    f32x4 acc[2][2] = {};
    for (int k0 = 0; k0 < K; k0 += BK) {
        for (int l = tid; l < BM * BK; l += 256) {
            int r = l >> 5, c = l & 31;
            int gr = row0 + r, gk = k0 + c;
            float v = (gr < M && gk < K) ? A[(size_t)gr * lda + gk] : 0.f;
            As[r][c] = (_Float16)v;
        }
        for (int l = tid; l < BK * BN; l += 256) {
            int kk = l >> 6, nn = l & 63;
            int gk = k0 + kk, gn = col0 + nn;
            float v = (gk < K && gn < N) ? B[(size_t)gk * ldb + gn] : 0.f;
            Bs[nn][kk] = (_Float16)v;
        }
        __syncthreads();
        f16x8 af[2], bf[2];
#pragma unroll
        for (int i = 0; i < 2; ++i) af[i] = *(const f16x8*)&As[wr * 32 + i * 16 + r16][g * 8];
#pragma unroll
        for (int j = 0; j < 2; ++j) bf[j] = *(const f16x8*)&Bs[wc * 32 + j * 16 + r16][g * 8];
#pragma unroll
        for (int i = 0; i < 2; ++i)
#pragma unroll
            for (int j = 0; j < 2; ++j)
                acc[i][j] = __builtin_amdgcn_mfma_f32_16x16x32_f16(af[i], bf[j], acc[i][j], 0, 0, 0);
        __syncthreads();
    }
#pragma unroll
    for (int i = 0; i < 2; ++i)
#pragma unroll
        for (int j = 0; j < 2; ++j) {
            int gc = col0 + wc * 32 + j * 16 + r16;
            if (gc >= N) continue;
#pragma unroll
            for (int rr = 0; rr < 4; ++rr) {
                int gr = row0 + wr * 32 + i * 16 + g * 4 + rr;
                if (gr < M) C[(size_t)gr * ldc + gc] = (CT)acc[i][j][rr];
            }
        }
}

// ---------------- counting / hierarchical scan / scatter ----------------
__global__ void count_idx(const int* __restrict__ idx, int n, int* __restrict__ cnt)
{
    int i = blockIdx.x * 256 + threadIdx.x;
    if (i < n) atomicAdd(&cnt[idx[i]], 1);
}

__global__ __launch_bounds__(1024) void scan1(const int* __restrict__ in, int* __restrict__ out,
                                              int* __restrict__ part, int n)
{
    __shared__ int wsum[16];
    const int tid = threadIdx.x, lane = tid & 63, wv = tid >> 6;
    int i = blockIdx.x * 1024 + tid;
    int v = (i < n) ? in[i] : 0;
    int acc = v;
#pragma unroll
    for (int off = 1; off < 64; off <<= 1) {
        int t = __shfl_up(acc, off);
        if (lane >= off) acc += t;
    }
    if (lane == 63) wsum[wv] = acc;
    __syncthreads();
    if (wv == 0 && lane < 16) {
        int s = wsum[lane];
        int a2 = s;
#pragma unroll
        for (int off = 1; off < 16; off <<= 1) {
            int t = __shfl_up(a2, off);
            if (lane >= off) a2 += t;
        }
        wsum[lane] = a2 - s;
    }
    __syncthreads();
    int ex = wsum[wv] + acc - v;
    if (i < n) out[i] = ex;
    if (part && tid == 1023) part[blockIdx.x] = ex + v;
}

__global__ void scan_add(int* __restrict__ out, const int* __restrict__ part, int n)
{
    int i = blockIdx.x * 1024 + threadIdx.x;
    if (i < n) out[i] += part[blockIdx.x];
}

__global__ void scatter_edges(const int* __restrict__ src, const int* __restrict__ dst, int E,
                              const int* __restrict__ doff, int* __restrict__ cur,
                              int* __restrict__ ss, int* __restrict__ sd)
{
    int e = blockIdx.x * 256 + threadIdx.x;
    if (e >= E) return;
    int d = dst[e];
    int pos = doff[d] + atomicAdd(&cur[d], 1);
    ss[pos] = src[e];   // edges sorted by dst (CSR)
    sd[pos] = d;
}

// ---------------- per-edge softmax (with 1/(deg_dst+1) folded), fp16 store ----------------
__global__ __launch_bounds__(256) void q_kernel(
    const int* __restrict__ ss, const int* __restrict__ sd, int E,
    const float* __restrict__ xu, const float* __restrict__ cvec,
    const int* __restrict__ indeg, _Float16* __restrict__ Q)
{
    int e = blockIdx.x * 256 + threadIdx.x;
    if (e >= E) return;
    int s = ss[e], d = sd[e];
    float t[NH];
    float m = -1e30f;
#pragma unroll
    for (int h = 0; h < NH; ++h) {
        t[h] = xu[(size_t)s * NH + h] - xu[(size_t)d * NH + h] + cvec[h];
        m = fmaxf(m, t[h]);
    }
    float den = 0.f;
#pragma unroll
    for (int h = 0; h < NH; ++h) { t[h] = __expf(t[h] - m); den += t[h]; }
    float sc = 1.f / (den * (float)(indeg[d] + 1));
#pragma unroll
    for (int h = 0; h < NH; ++h) Q[(size_t)e * NH + h] = (_Float16)(t[h] * sc);
}

// ---------------- CSR segmented aggregate + self-loop + mean + bias + act, fused ----------------
// One thread per (dst, channel); edges for a dst are contiguous (dst-sorted).
// No atomics: plain coalesced store. Self-loop = softmax(c)/(deg+1) * xw[d].
template <int OUT>
__global__ __launch_bounds__(256) void feast_aggfin(
    const int* __restrict__ doff, const int* __restrict__ cnt, const int* __restrict__ ssrc,
    const _Float16* __restrict__ Q, const _Float16* __restrict__ xw,
    const float* __restrict__ cvec, const float* __restrict__ bias,
    float* __restrict__ outp, int n, int ldo, int col0, int act)
{
    size_t tid = (size_t)blockIdx.x * 256 + threadIdx.x;
    int d = (int)(tid / OUT);
    int o = (int)(tid % OUT);
    if (d >= n) return;
    int beg = doff[d], deg = cnt[d];
    float acc = 0.f;
    for (int e = beg; e < beg + deg; ++e) {
        int s = ssrc[e];
        const _Float16* qe = Q + (size_t)e * NH;
        const _Float16* xws = xw + (size_t)s * (NH * OUT) + o;
        float a = 0.f;
#pragma unroll
        for (int h = 0; h < NH; ++h) a += (float)qe[h] * (float)xws[h * OUT];
        acc += a;
    }
    // self-loop: softmax(c) (x_j - x_i = 0)
    float t[NH];
    float m = -1e30f;
#pragma unroll
    for (int h = 0; h < NH; ++h) { t[h] = cvec[h]; m = fmaxf(m, t[h]); }
    float den = 0.f;
#pragma unroll
    for (int h = 0; h < NH; ++h) { t[h] = __expf(t[h] - m); den += t[h]; }
    float sc = 1.f / (den * (float)(deg + 1));
    const _Float16* xwd = xw + (size_t)d * (NH * OUT) + o;
    float ms = 0.f;
#pragma unroll
    for (int h = 0; h < NH; ++h) ms += t[h] * (float)xwd[h * OUT];
    float v = acc + ms * sc + bias[o];
    if (act) v = v > 0.f ? v : 0.1f * v;
    outp[(size_t)d * ldo + col0 + o] = v;
}

// ---------------- pooling / unpooling ----------------
__global__ void pool_scatter(const float* __restrict__ xin, int ldx, const int* __restrict__ clust,
                             float* __restrict__ pooled, int C, int n)
{
    size_t tid = (size_t)blockIdx.x * 256 + threadIdx.x;
    int i = (int)(tid / C), c = (int)(tid % C);
    if (i >= n) return;
    atomicAdd(&pooled[(size_t)clust[i] * C + c], xin[(size_t)i * ldx + c]);
}

__global__ void pool_div(float* __restrict__ pooled, const int* __restrict__ pcnt, int C, int m)
{
    size_t tid = (size_t)blockIdx.x * 256 + threadIdx.x;
    int j = (int)(tid / C);
    if (j >= m) return;
    pooled[tid] /= fmaxf((float)pcnt[j], 1.f);
}

__global__ void gather_rows(const float* __restrict__ xin, int ldx, const int* __restrict__ idx,
                            float* __restrict__ outp, int C, int n)
{
    size_t tid = (size_t)blockIdx.x * 256 + threadIdx.x;
    int i = (int)(tid / C), c = (int)(tid % C);
    if (i >= n) return;
    outp[tid] = xin[(size_t)idx[i] * ldx + c];
}

// ---------------- fc1 weight -> fp16 transposed [1024][32] ----------------
__global__ void w1_to_f16t(const float* __restrict__ w1, _Float16* __restrict__ w1t)
{
    int i = blockIdx.x * 256 + threadIdx.x;
    if (i >= 32 * 1024) return;
    int n = i >> 5, k = i & 31;
    w1t[i] = (_Float16)w1[k * 1024 + n];
}

// ---------------- fused FC head via f16 MFMA: lrelu(y@W1+b1)@W2+b2, row-normalize ----------------
__global__ __launch_bounds__(256) void fc_head2(
    const float* __restrict__ yin, const _Float16* __restrict__ w1t,
    const float* __restrict__ b1, const float* __restrict__ w2,
    const float* __restrict__ b2, float* __restrict__ outp, int n)
{
    const int lane = threadIdx.x & 63, wv = threadIdx.x >> 6;
    const int g = lane >> 4, r16 = lane & 15;
    const int node0 = blockIdx.x * 64 + wv * 16;

    f16x8 afrag;
    int anode = node0 + r16;
    if (anode < n) {
        const float* yr = yin + (size_t)anode * 32 + g * 8;
#pragma unroll
        for (int j = 0; j < 8; ++j) afrag[j] = (_Float16)yr[j];
    } else {
#pragma unroll
        for (int j = 0; j < 8; ++j) afrag[j] = (_Float16)0.f;
    }

    float o0[4] = {0.f, 0.f, 0.f, 0.f};
    float o1[4] = {0.f, 0.f, 0.f, 0.f};
    float o2[4] = {0.f, 0.f, 0.f, 0.f};
    const f32x4 zero4 = {0.f, 0.f, 0.f, 0.f};

#pragma unroll 2
    for (int t = 0; t < 64; ++t) {
        const f16x8 bfrag = *(const f16x8*)(w1t + ((size_t)(t * 16 + r16)) * 32 + g * 8);
        f32x4 d = __builtin_amdgcn_mfma_f32_16x16x32_f16(afrag, bfrag, zero4, 0, 0, 0);
        int kh = t * 16 + r16;
        float b1v = b1[kh];
        float w20 = w2[kh * 3], w21 = w2[kh * 3 + 1], w22 = w2[kh * 3 + 2];
#pragma unroll
        for (int r = 0; r < 4; ++r) {
            float h = d[r] + b1v;
            h = h > 0.f ? h : 0.1f * h;
            o0[r] += h * w20;
            o1[r] += h * w21;
            o2[r] += h * w22;
        }
    }
#pragma unroll
    for (int r = 0; r < 4; ++r) {
#pragma unroll
        for (int off = 1; off < 16; off <<= 1) {
            o0[r] += __shfl_xor(o0[r], off);
            o1[r] += __shfl_xor(o1[r], off);
            o2[r] += __shfl_xor(o2[r], off);
        }
    }
    if (r16 == 0) {
#pragma unroll
        for (int r = 0; r < 4; ++r) {
            int node = node0 + g * 4 + r;
            if (node >= n) continue;
            float v0 = o0[r] + b2[0];
            float v1 = o1[r] + b2[1];
            float v2 = o2[r] + b2[2];
            float nr = fmaxf(sqrtf(v0 * v0 + v1 * v1 + v2 * v2), 1e-12f);
            outp[(size_t)node * 3 + 0] = v0 / nr;
            outp[(size_t)node * 3 + 1] = v1 / nr;
            outp[(size_t)node * 3 + 2] = v2 / nr;
        }
    }
}

// ---------------- dispatch helpers ----------------
static void launch_aggfin(int outC, const int* doff, const int* cnt, const int* ss,
                          const _Float16* Q, const _Float16* xw, const float* cvec,
                          const float* bias, float* outp, int n, int ldo, int col0,
                          int act, hipStream_t stream)
{
    dim3 g(ceil_div((size_t)n * outC, 256));
    if (outC == 32)       feast_aggfin<32><<<g, 256, 0, stream>>>(doff, cnt, ss, Q, xw, cvec, bias, outp, n, ldo, col0, act);
    else if (outC == 64)  feast_aggfin<64><<<g, 256, 0, stream>>>(doff, cnt, ss, Q, xw, cvec, bias, outp, n, ldo, col0, act);
    else                  feast_aggfin<128><<<g, 256, 0, stream>>>(doff, cnt, ss, Q, xw, cvec, bias, outp, n, ldo, col0, act);
}

extern "C" void kernel_launch(void* const* d_in, const int* in_sizes, int n_in,
                              void* d_out, int out_size, void* d_ws, size_t ws_size,
                              hipStream_t stream)
{
    const float* x      = (const float*)d_in[0];
    const int*   ei1    = (const int*)d_in[1];
    const int*   ei2    = (const int*)d_in[2];
    const int*   ei3    = (const int*)d_in[3];
    const int*   clust2 = (const int*)d_in[4];
    const int*   clust3 = (const int*)d_in[5];
    const float* lp[8][4];
    for (int i = 0; i < 8; ++i)
        for (int j = 0; j < 4; ++j)
            lp[i][j] = (const float*)d_in[6 + i * 4 + j];  // l1..l4,r1..r4 x {u,c,w,b}
    const float* fc1_w = (const float*)d_in[38];
    const float* fc1_b = (const float*)d_in[39];
    const float* fc2_w = (const float*)d_in[40];
    const float* fc2_b = (const float*)d_in[41];
    float* out = (float*)d_out;

    // ---- workspace layout (~175 MB) ----
    char* ws = (char*)d_ws;
    size_t off = 0;
    auto alloc = [&](size_t b) { size_t p = off; off += (b + 255) & ~(size_t)255; return p; };
    _Float16* XWH = (_Float16*)(ws + alloc((size_t)cN1 * NH * 32 * 2));  // 57.6 MB (max xw, fp16)
    _Float16* Q   = (_Float16*)(ws + alloc((size_t)cE1 * NH * 2));       // 21.6 MB
    float* GATH  = (float*)(ws + alloc((size_t)cN1 * 64 * 4));           // 25.6 MB (pool/unpool scratch; YB alias)
    float* X1CAT = (float*)(ws + alloc((size_t)cN1 * 64 * 4));           // 25.6 MB
    float* X2CAT = (float*)(ws + alloc((size_t)cN2 * 128 * 4));          // 12.8 MB
    float* X2B   = (float*)(ws + alloc((size_t)cN2 * 64 * 4));           // 6.4 MB
    float* X3    = (float*)(ws + alloc((size_t)cN3 * 128 * 4));          // 3.2 MB
    float* XU    = (float*)(ws + alloc((size_t)cN1 * NH * 4));           // 3.6 MB
    int* SS1 = (int*)(ws + alloc((size_t)cE1 * 4));
    int* SD1 = (int*)(ws + alloc((size_t)cE1 * 4));
    int* SS2 = (int*)(ws + alloc((size_t)cE2 * 4));
    int* SD2 = (int*)(ws + alloc((size_t)cE2 * 4));
    int* SS3 = (int*)(ws + alloc((size_t)cE3 * 4));
    int* SD3 = (int*)(ws + alloc((size_t)cE3 * 4));
    int* DOFF1 = (int*)(ws + alloc((size_t)cN1 * 4));
    int* DOFF2 = (int*)(ws + alloc((size_t)cN2 * 4));
    int* DOFF3 = (int*)(ws + alloc((size_t)cN3 * 4));
    int* CNT1 = (int*)(ws + alloc((size_t)cN1 * 4));
    int* CNT2 = (int*)(ws + alloc((size_t)cN2 * 4));
    int* CNT3 = (int*)(ws + alloc((size_t)cN3 * 4));
    int* CUR  = (int*)(ws + alloc((size_t)cN1 * 4));
    int* PC2  = (int*)(ws + alloc((size_t)cN2 * 4));
    int* PC3  = (int*)(ws + alloc((size_t)cN3 * 4));
    int* PART = (int*)(ws + alloc(1024 * 4));
    _Float16* W1T = (_Float16*)(ws + alloc((size_t)32 * 1024 * 2));
    float* YB = GATH;  // r4 output aliases scratch (free by then)

    auto run_scan = [&](const int* in, int* outp, int n) {
        int nb = (n + 1023) / 1024;
        scan1<<<nb, 1024, 0, stream>>>(in, outp, nb > 1 ? PART : nullptr, n);
        if (nb > 1) {
            scan1<<<1, 1024, 0, stream>>>(PART, PART, nullptr, nb);
            scan_add<<<nb, 1024, 0, stream>>>(outp, PART, n);
        }
    };

    // ---- dst-degree counts + dst-sort (CSR) for all three edge lists ----
    hipMemsetAsync(CNT1, 0, (size_t)cN1 * 4, stream);
    hipMemsetAsync(CNT2, 0, (size_t)cN2 * 4, stream);
    hipMemsetAsync(CNT3, 0, (size_t)cN3 * 4, stream);
    count_idx<<<ceil_div(cE1, 256), 256, 0, stream>>>(ei1 + cE1, cE1, CNT1);
    count_idx<<<ceil_div(cE2, 256), 256, 0, stream>>>(ei2 + cE2, cE2, CNT2);
    count_idx<<<ceil_div(cE3, 256), 256, 0, stream>>>(ei3 + cE3, cE3, CNT3);
    run_scan(CNT1, DOFF1, cN1);
    run_scan(CNT2, DOFF2, cN2);
    run_scan(CNT3, DOFF3, cN3);
    hipMemsetAsync(CUR, 0, (size_t)cN1 * 4, stream);
    scatter_edges<<<ceil_div(cE1, 256), 256, 0, stream>>>(ei1, ei1 + cE1, cE1, DOFF1, CUR, SS1, SD1);
    hipMemsetAsync(CUR, 0, (size_t)cN2 * 4, stream);
    scatter_edges<<<ceil_div(cE2, 256), 256, 0, stream>>>(ei2, ei2 + cE2, cE2, DOFF2, CUR, SS2, SD2);
    hipMemsetAsync(CUR, 0, (size_t)cN3 * 4, stream);
    scatter_edges<<<ceil_div(cE3, 256), 256, 0, stream>>>(ei3, ei3 + cE3, cE3, DOFF3, CUR, SS3, SD3);

    // fc1 weights -> fp16 transposed
    w1_to_f16t<<<ceil_div(32 * 1024, 256), 256, 0, stream>>>(fc1_w, W1T);

    auto feast = [&](const float* xin, int ldx, int n, int cin, int outC,
                     const int* ss, const int* sd, const int* doff, const int* cnt, int E,
                     const float* const* L, float* dstp, int ldo, int col0, int act) {
        // xu = xin @ u  [n, 9]  (fp32 out)
        gemm_mfma<float><<<dim3(1, ceil_div(n, 64)), 256, 0, stream>>>(xin, ldx, L[0], NH, XU, NH, n, NH, cin);
        // xw = xin @ W  [n, 9*outC]  (fp16 out)
        int NC = NH * outC;
        gemm_mfma<_Float16><<<dim3(ceil_div(NC, 64), ceil_div(n, 64)), 256, 0, stream>>>(xin, ldx, L[2], NC, XWH, NC, n, NC, cin);
        // per-edge softmax with 1/(deg+1) folded
        q_kernel<<<ceil_div(E, 256), 256, 0, stream>>>(ss, sd, E, XU, L[1], cnt, Q);
        // CSR aggregate + self-loop + bias + act, fused
        launch_aggfin(outC, doff, cnt, ss, Q, XWH, L[1], L[3], dstp, n, ldo, col0, act, stream);
    };

    // l1: [N1,6] -> [N1,32] into X1CAT[:, 0:32]
    feast(x, 6, cN1, 6, 32, SS1, SD1, DOFF1, CNT1, cE1, lp[0], X1CAT, 64, 0, 1);

    // pool -> [N2,32] in GATH
    hipMemsetAsync(PC2, 0, (size_t)cN2 * 4, stream);
    hipMemsetAsync(GATH, 0, (size_t)cN2 * 32 * 4, stream);
    count_idx<<<ceil_div(cN1, 256), 256, 0, stream>>>(clust2, cN1, PC2);
    pool_scatter<<<ceil_div((size_t)cN1 * 32, 256), 256, 0, stream>>>(X1CAT, 64, clust2, GATH, 32, cN1);
    pool_div<<<ceil_div((size_t)cN2 * 32, 256), 256, 0, stream>>>(GATH, PC2, 32, cN2);

    // l2: [N2,32] -> [N2,64] into X2CAT[:, 0:64]
    feast(GATH, 32, cN2, 32, 64, SS2, SD2, DOFF2, CNT2, cE2, lp[1], X2CAT, 128, 0, 1);

    // pool -> [N3,64] in GATH
    hipMemsetAsync(PC3, 0, (size_t)cN3 * 4, stream);
    hipMemsetAsync(GATH, 0, (size_t)cN3 * 64 * 4, stream);
    count_idx<<<ceil_div(cN2, 256), 256, 0, stream>>>(clust3, cN2, PC3);
    pool_scatter<<<ceil_div((size_t)cN2 * 64, 256), 256, 0, stream>>>(X2CAT, 128, clust3, GATH, 64, cN2);
    pool_div<<<ceil_div((size_t)cN3 * 64, 256), 256, 0, stream>>>(GATH, PC3, 64, cN3);

    // l3: [N3,64] -> [N3,128] into X3
    feast(GATH, 64, cN3, 64, 128, SS3, SD3, DOFF3, CNT3, cE3, lp[2], X3, 128, 0, 1);
    // l4: [N3,128] -> [N3,128] in-place (X3 consumed by gemms before aggfin writes)
    feast(X3, 128, cN3, 128, 128, SS3, SD3, DOFF3, CNT3, cE3, lp[3], X3, 128, 0, 1);

    // r1: unpool x3 -> [N2,128], feast -> X2CAT[:, 64:128] (no act)
    gather_rows<<<ceil_div((size_t)cN2 * 128, 256), 256, 0, stream>>>(X3, 128, clust3, GATH, 128, cN2);
    feast(GATH, 128, cN2, 128, 64, SS2, SD2, DOFF2, CNT2, cE2, lp[4], X2CAT, 128, 64, 0);

    // r2: [N2,128] -> [N2,64] into X2B
    feast(X2CAT, 128, cN2, 128, 64, SS2, SD2, DOFF2, CNT2, cE2, lp[5], X2B, 64, 0, 1);

    // r3: unpool x2 -> [N1,64], feast -> X1CAT[:, 32:64] (no act)
    gather_rows<<<ceil_div((size_t)cN1 * 64, 256), 256, 0, stream>>>(X2B, 64, clust2, GATH, 64, cN1);
    feast(GATH, 64, cN1, 64, 32, SS1, SD1, DOFF1, CNT1, cE1, lp[6], X1CAT, 64, 32, 0);

    // r4: [N1,64] -> [N1,32] into YB
    feast(X1CAT, 64, cN1, 64, 32, SS1, SD1, DOFF1, CNT1, cE1, lp[7], YB, 32, 0, 1);

    // fused FC head + normalize (f16 MFMA)
    fc_head2<<<ceil_div(cN1, 64), 256, 0, stream>>>(YB, W1T, fc1_b, fc2_w, fc2_b, out, cN1);

    (void)in_sizes; (void)n_in; (void)out_size; (void)ws_size;
}

// Round 6
// 1382.517 us; speedup vs baseline: 2.8940x; 1.0475x over previous
//
#include <hip/hip_runtime.h>
#include <cstddef>
#include <cstdint>

#define NH 9
#define QLD 10  // Q/xu row stride in fp16 (9 + 1 pad -> 20B rows, 4B aligned)

typedef _Float16 f16x8 __attribute__((ext_vector_type(8)));
typedef _Float16 f16x2 __attribute__((ext_vector_type(2)));
typedef float f32x4 __attribute__((ext_vector_type(4)));

static const int cN1 = 100000, cN2 = 25000, cN3 = 6250;
static const int cE1 = 1200000, cE2 = 300000, cE3 = 75000;

static inline unsigned ceil_div(size_t a, size_t b) { return (unsigned)((a + b - 1) / b); }

// ---------------- f16 MFMA GEMM: C[M,N] = A[M,K](f32,lda) @ B[K,N](f32,ldb) ----------------
// Optional ridx: A row gr reads A[ridx[gr]] (fuses unpool-gather into the GEMM).
// Fragment layout verified numerically (fc_head2 r3-r5): A row=lane&15, k=(lane>>4)*8+j;
// B col=lane&15 same k; D col=lane&15, row=(lane>>4)*4+reg.
template <typename CT>
__global__ __launch_bounds__(256) void gemm_mfma(
    const float* __restrict__ A, int lda, const int* __restrict__ ridx,
    const float* __restrict__ B, int ldb,
    CT* __restrict__ C, int ldc, int M, int N, int K)
{
    const int BM = 64, BN = 64, BK = 32, LK = 40;
    __shared__ _Float16 As[BM][LK];
    __shared__ _Float16 Bs[BN][LK];  // transposed: Bs[n][k]
    const int tid = threadIdx.x;
    const int row0 = blockIdx.y * BM, col0 = blockIdx.x * BN;
    const int lane = tid & 63, wv = tid >> 6;
    const int g = lane >> 4, r16 = lane & 15;
    const int wr = wv >> 1, wc = wv & 1;
    f32x4 acc[2][2] = {};
    for (int k0 = 0; k0 < K; k0 += BK) {
        for (int l = tid; l < BM * BK; l += 256) {
            int r = l >> 5, c = l & 31;
            int gr = row0 + r, gk = k0 + c;
            float v = 0.f;
            if (gr < M && gk < K) {
                int ar = ridx ? ridx[gr] : gr;
                v = A[(size_t)ar * lda + gk];
            }
            As[r][c] = (_Float16)v;
        }
        for (int l = tid; l < BK * BN; l += 256) {
            int kk = l >> 6, nn = l & 63;
            int gk = k0 + kk, gn = col0 + nn;
            float v = (gk < K && gn < N) ? B[(size_t)gk * ldb + gn] : 0.f;
            Bs[nn][kk] = (_Float16)v;
        }
        __syncthreads();
        f16x8 af[2], bf[2];
#pragma unroll
        for (int i = 0; i < 2; ++i) af[i] = *(const f16x8*)&As[wr * 32 + i * 16 + r16][g * 8];
#pragma unroll
        for (int j = 0; j < 2; ++j) bf[j] = *(const f16x8*)&Bs[wc * 32 + j * 16 + r16][g * 8];
#pragma unroll
        for (int i = 0; i < 2; ++i)
#pragma unroll
            for (int j = 0; j < 2; ++j)
                acc[i][j] = __builtin_amdgcn_mfma_f32_16x16x32_f16(af[i], bf[j], acc[i][j], 0, 0, 0);
        __syncthreads();
    }
#pragma unroll
    for (int i = 0; i < 2; ++i)
#pragma unroll
        for (int j = 0; j < 2; ++j) {
            int gc = col0 + wc * 32 + j * 16 + r16;
            if (gc >= N) continue;
#pragma unroll
            for (int rr = 0; rr < 4; ++rr) {
                int gr = row0 + wr * 32 + i * 16 + g * 4 + rr;
                if (gr < M) C[(size_t)gr * ldc + gc] = (CT)acc[i][j][rr];
            }
        }
}

// ---------------- counting / hierarchical scan / scatter ----------------
__global__ void count_idx(const int* __restrict__ idx, int n, int* __restrict__ cnt)
{
    int i = blockIdx.x * 256 + threadIdx.x;
    if (i < n) atomicAdd(&cnt[idx[i]], 1);
}

__global__ __launch_bounds__(1024) void scan1(const int* __restrict__ in, int* __restrict__ out,
                                              int* __restrict__ part, int n)
{
    __shared__ int wsum[16];
    const int tid = threadIdx.x, lane = tid & 63, wv = tid >> 6;
    int i = blockIdx.x * 1024 + tid;
    int v = (i < n) ? in[i] : 0;
    int acc = v;
#pragma unroll
    for (int off = 1; off < 64; off <<= 1) {
        int t = __shfl_up(acc, off);
        if (lane >= off) acc += t;
    }
    if (lane == 63) wsum[wv] = acc;
    __syncthreads();
    if (wv == 0 && lane < 16) {
        int s = wsum[lane];
        int a2 = s;
#pragma unroll
        for (int off = 1; off < 16; off <<= 1) {
            int t = __shfl_up(a2, off);
            if (lane >= off) a2 += t;
        }
        wsum[lane] = a2 - s;
    }
    __syncthreads();
    int ex = wsum[wv] + acc - v;
    if (i < n) out[i] = ex;
    if (part && tid == 1023) part[blockIdx.x] = ex + v;
}

__global__ void scan_add(int* __restrict__ out, const int* __restrict__ part, int n)
{
    int i = blockIdx.x * 1024 + threadIdx.x;
    if (i < n) out[i] += part[blockIdx.x];
}

__global__ void scatter_edges(const int* __restrict__ src, const int* __restrict__ dst, int E,
                              const int* __restrict__ doff, int* __restrict__ cur,
                              int* __restrict__ ss, int* __restrict__ sd)
{
    int e = blockIdx.x * 256 + threadIdx.x;
    if (e >= E) return;
    int d = dst[e];
    int pos = doff[d] + atomicAdd(&cur[d], 1);
    ss[pos] = src[e];   // edges sorted by dst (CSR)
    sd[pos] = d;
}

// ---------------- per-edge softmax (1/(deg_dst+1) folded), fp16 in/out, padded rows ----------------
__global__ __launch_bounds__(256) void q_kernel2(
    const int* __restrict__ ss, const int* __restrict__ sd, int E,
    const _Float16* __restrict__ xuh, const float* __restrict__ cvec,
    const int* __restrict__ indeg, _Float16* __restrict__ Q)
{
    int e = blockIdx.x * 256 + threadIdx.x;
    if (e >= E) return;
    int s = ss[e], d = sd[e];
    const f16x2* us = (const f16x2*)(xuh + (size_t)s * QLD);
    const f16x2* ud = (const f16x2*)(xuh + (size_t)d * QLD);
    float t[NH];
    float m = -1e30f;
#pragma unroll
    for (int i = 0; i < 4; ++i) {
        f16x2 a = us[i], b = ud[i];
        t[2 * i]     = (float)a[0] - (float)b[0] + cvec[2 * i];
        t[2 * i + 1] = (float)a[1] - (float)b[1] + cvec[2 * i + 1];
    }
    t[8] = (float)us[4][0] - (float)ud[4][0] + cvec[8];
#pragma unroll
    for (int h = 0; h < NH; ++h) m = fmaxf(m, t[h]);
    float den = 0.f;
#pragma unroll
    for (int h = 0; h < NH; ++h) { t[h] = __expf(t[h] - m); den += t[h]; }
    float sc = 1.f / (den * (float)(indeg[d] + 1));
    f16x2* qo = (f16x2*)(Q + (size_t)e * QLD);
#pragma unroll
    for (int i = 0; i < 4; ++i) {
        f16x2 r;
        r[0] = (_Float16)(t[2 * i] * sc);
        r[1] = (_Float16)(t[2 * i + 1] * sc);
        qo[i] = r;
    }
    f16x2 r4;
    r4[0] = (_Float16)(t[8] * sc);
    r4[1] = (_Float16)0.f;
    qo[4] = r4;
}

// ---------------- CSR segmented aggregate + self-loop + bias + act, fused ----------------
// One lane per (dst, channel-pair): f16x2 loads, 2-edge unroll for MLP. No atomics.
template <int OUT>
__global__ __launch_bounds__(256) void feast_aggfin2(
    const int* __restrict__ doff, const int* __restrict__ cnt, const int* __restrict__ ssrc,
    const _Float16* __restrict__ Q, const _Float16* __restrict__ xw,
    const float* __restrict__ cvec, const float* __restrict__ bias,
    float* __restrict__ outp, int n, int ldo, int col0, int act)
{
    const int L = OUT / 2;          // lanes per dst
    const int ldx = NH * OUT;       // xw row stride (fp16 elements)
    size_t tid = (size_t)blockIdx.x * 256 + threadIdx.x;
    int d = (int)(tid / L);
    int p = (int)(tid % L);
    if (d >= n) return;
    int beg = doff[d], deg = cnt[d];
    int end = beg + deg;
    float ax = 0.f, ay = 0.f;
    int e = beg;
    for (; e + 2 <= end; e += 2) {
        int s0 = ssrc[e], s1 = ssrc[e + 1];
        const f16x2* q0 = (const f16x2*)(Q + (size_t)e * QLD);
        const f16x2* q1 = (const f16x2*)(Q + (size_t)(e + 1) * QLD);
        const f16x2* x0 = (const f16x2*)(xw + (size_t)s0 * ldx) + p;
        const f16x2* x1 = (const f16x2*)(xw + (size_t)s1 * ldx) + p;
        f16x2 qa[5], qb[5], xa[NH], xb[NH];
#pragma unroll
        for (int i = 0; i < 5; ++i) { qa[i] = q0[i]; qb[i] = q1[i]; }
#pragma unroll
        for (int h = 0; h < NH; ++h) { xa[h] = x0[h * (OUT / 2)]; xb[h] = x1[h * (OUT / 2)]; }
#pragma unroll
        for (int h = 0; h < NH; ++h) {
            float qh0 = (float)qa[h >> 1][h & 1];
            float qh1 = (float)qb[h >> 1][h & 1];
            ax += qh0 * (float)xa[h][0] + qh1 * (float)xb[h][0];
            ay += qh0 * (float)xa[h][1] + qh1 * (float)xb[h][1];
        }
    }
    if (e < end) {
        int s0 = ssrc[e];
        const f16x2* q0 = (const f16x2*)(Q + (size_t)e * QLD);
        const f16x2* x0 = (const f16x2*)(xw + (size_t)s0 * ldx) + p;
        f16x2 qa[5], xa[NH];
#pragma unroll
        for (int i = 0; i < 5; ++i) qa[i] = q0[i];
#pragma unroll
        for (int h = 0; h < NH; ++h) xa[h] = x0[h * (OUT / 2)];
#pragma unroll
        for (int h = 0; h < NH; ++h) {
            float qh0 = (float)qa[h >> 1][h & 1];
            ax += qh0 * (float)xa[h][0];
            ay += qh0 * (float)xa[h][1];
        }
    }
    // self-loop: softmax(c)/(deg+1) * xw[d]
    float t[NH];
    float m = -1e30f;
#pragma unroll
    for (int h = 0; h < NH; ++h) { t[h] = cvec[h]; m = fmaxf(m, t[h]); }
    float den = 0.f;
#pragma unroll
    for (int h = 0; h < NH; ++h) { t[h] = __expf(t[h] - m); den += t[h]; }
    float sc = 1.f / (den * (float)(deg + 1));
    const f16x2* xd = (const f16x2*)(xw + (size_t)d * ldx) + p;
    float mx = 0.f, my = 0.f;
#pragma unroll
    for (int h = 0; h < NH; ++h) {
        f16x2 v = xd[h * (OUT / 2)];
        mx += t[h] * (float)v[0];
        my += t[h] * (float)v[1];
    }
    float vx = ax + mx * sc + bias[2 * p];
    float vy = ay + my * sc + bias[2 * p + 1];
    if (act) {
        vx = vx > 0.f ? vx : 0.1f * vx;
        vy = vy > 0.f ? vy : 0.1f * vy;
    }
    float2* op = (float2*)(outp + (size_t)d * ldo + col0) + p;
    *op = make_float2(vx, vy);
}

// ---------------- pooling ----------------
__global__ void pool_scatter(const float* __restrict__ xin, int ldx, const int* __restrict__ clust,
                             float* __restrict__ pooled, int C, int n)
{
    size_t tid = (size_t)blockIdx.x * 256 + threadIdx.x;
    int i = (int)(tid / C), c = (int)(tid % C);
    if (i >= n) return;
    atomicAdd(&pooled[(size_t)clust[i] * C + c], xin[(size_t)i * ldx + c]);
}

__global__ void pool_div(float* __restrict__ pooled, const int* __restrict__ pcnt, int C, int m)
{
    size_t tid = (size_t)blockIdx.x * 256 + threadIdx.x;
    int j = (int)(tid / C);
    if (j >= m) return;
    pooled[tid] /= fmaxf((float)pcnt[j], 1.f);
}

// ---------------- fc1 weight -> fp16 transposed [1024][32] ----------------
__global__ void w1_to_f16t(const float* __restrict__ w1, _Float16* __restrict__ w1t)
{
    int i = blockIdx.x * 256 + threadIdx.x;
    if (i >= 32 * 1024) return;
    int n = i >> 5, k = i & 31;
    w1t[i] = (_Float16)w1[k * 1024 + n];
}

// ---------------- fused FC head via f16 MFMA: lrelu(y@W1+b1)@W2+b2, row-normalize ----------------
__global__ __launch_bounds__(256) void fc_head2(
    const float* __restrict__ yin, const _Float16* __restrict__ w1t,
    const float* __restrict__ b1, const float* __restrict__ w2,
    const float* __restrict__ b2, float* __restrict__ outp, int n)
{
    const int lane = threadIdx.x & 63, wv = threadIdx.x >> 6;
    const int g = lane >> 4, r16 = lane & 15;
    const int node0 = blockIdx.x * 64 + wv * 16;

    f16x8 afrag;
    int anode = node0 + r16;
    if (anode < n) {
        const float* yr = yin + (size_t)anode * 32 + g * 8;
#pragma unroll
        for (int j = 0; j < 8; ++j) afrag[j] = (_Float16)yr[j];
    } else {
#pragma unroll
        for (int j = 0; j < 8; ++j) afrag[j] = (_Float16)0.f;
    }

    float o0[4] = {0.f, 0.f, 0.f, 0.f};
    float o1[4] = {0.f, 0.f, 0.f, 0.f};
    float o2[4] = {0.f, 0.f, 0.f, 0.f};
    const f32x4 zero4 = {0.f, 0.f, 0.f, 0.f};

#pragma unroll 2
    for (int t = 0; t < 64; ++t) {
        const f16x8 bfrag = *(const f16x8*)(w1t + ((size_t)(t * 16 + r16)) * 32 + g * 8);
        f32x4 d = __builtin_amdgcn_mfma_f32_16x16x32_f16(afrag, bfrag, zero4, 0, 0, 0);
        int kh = t * 16 + r16;
        float b1v = b1[kh];
        float w20 = w2[kh * 3], w21 = w2[kh * 3 + 1], w22 = w2[kh * 3 + 2];
#pragma unroll
        for (int r = 0; r < 4; ++r) {
            float h = d[r] + b1v;
            h = h > 0.f ? h : 0.1f * h;
            o0[r] += h * w20;
            o1[r] += h * w21;
            o2[r] += h * w22;
        }
    }
#pragma unroll
    for (int r = 0; r < 4; ++r) {
#pragma unroll
        for (int off = 1; off < 16; off <<= 1) {
            o0[r] += __shfl_xor(o0[r], off);
            o1[r] += __shfl_xor(o1[r], off);
            o2[r] += __shfl_xor(o2[r], off);
        }
    }
    if (r16 == 0) {
#pragma unroll
        for (int r = 0; r < 4; ++r) {
            int node = node0 + g * 4 + r;
            if (node >= n) continue;
            float v0 = o0[r] + b2[0];
            float v1 = o1[r] + b2[1];
            float v2 = o2[r] + b2[2];
            float nr = fmaxf(sqrtf(v0 * v0 + v1 * v1 + v2 * v2), 1e-12f);
            outp[(size_t)node * 3 + 0] = v0 / nr;
            outp[(size_t)node * 3 + 1] = v1 / nr;
            outp[(size_t)node * 3 + 2] = v2 / nr;
        }
    }
}

// ---------------- dispatch helper ----------------
static void launch_aggfin(int outC, const int* doff, const int* cnt, const int* ss,
                          const _Float16* Q, const _Float16* xw, const float* cvec,
                          const float* bias, float* outp, int n, int ldo, int col0,
                          int act, hipStream_t stream)
{
    dim3 g(ceil_div((size_t)n * (outC / 2), 256));
    if (outC == 32)       feast_aggfin2<32><<<g, 256, 0, stream>>>(doff, cnt, ss, Q, xw, cvec, bias, outp, n, ldo, col0, act);
    else if (outC == 64)  feast_aggfin2<64><<<g, 256, 0, stream>>>(doff, cnt, ss, Q, xw, cvec, bias, outp, n, ldo, col0, act);
    else                  feast_aggfin2<128><<<g, 256, 0, stream>>>(doff, cnt, ss, Q, xw, cvec, bias, outp, n, ldo, col0, act);
}

extern "C" void kernel_launch(void* const* d_in, const int* in_sizes, int n_in,
                              void* d_out, int out_size, void* d_ws, size_t ws_size,
                              hipStream_t stream)
{
    const float* x      = (const float*)d_in[0];
    const int*   ei1    = (const int*)d_in[1];
    const int*   ei2    = (const int*)d_in[2];
    const int*   ei3    = (const int*)d_in[3];
    const int*   clust2 = (const int*)d_in[4];
    const int*   clust3 = (const int*)d_in[5];
    const float* lp[8][4];
    for (int i = 0; i < 8; ++i)
        for (int j = 0; j < 4; ++j)
            lp[i][j] = (const float*)d_in[6 + i * 4 + j];  // l1..l4,r1..r4 x {u,c,w,b}
    const float* fc1_w = (const float*)d_in[38];
    const float* fc1_b = (const float*)d_in[39];
    const float* fc2_w = (const float*)d_in[40];
    const float* fc2_b = (const float*)d_in[41];
    float* out = (float*)d_out;

    // ---- workspace layout (~180 MB) ----
    char* ws = (char*)d_ws;
    size_t off = 0;
    auto alloc = [&](size_t b) { size_t p = off; off += (b + 255) & ~(size_t)255; return p; };
    _Float16* XWH = (_Float16*)(ws + alloc((size_t)cN1 * NH * 32 * 2));  // 57.6 MB (max xw, fp16)
    _Float16* Q   = (_Float16*)(ws + alloc((size_t)cE1 * QLD * 2));      // 24 MB (padded rows)
    _Float16* XUH = (_Float16*)(ws + alloc((size_t)cN1 * QLD * 2));      // 2 MB (fp16 xu, padded)
    float* GATH  = (float*)(ws + alloc((size_t)cN1 * 64 * 4));           // 25.6 MB (pool scratch; YB alias)
    float* X1CAT = (float*)(ws + alloc((size_t)cN1 * 64 * 4));           // 25.6 MB
    float* X2CAT = (float*)(ws + alloc((size_t)cN2 * 128 * 4));          // 12.8 MB
    float* X2B   = (float*)(ws + alloc((size_t)cN2 * 64 * 4));           // 6.4 MB
    float* X3    = (float*)(ws + alloc((size_t)cN3 * 128 * 4));          // 3.2 MB
    int* SS1 = (int*)(ws + alloc((size_t)cE1 * 4));
    int* SD1 = (int*)(ws + alloc((size_t)cE1 * 4));
    int* SS2 = (int*)(ws + alloc((size_t)cE2 * 4));
    int* SD2 = (int*)(ws + alloc((size_t)cE2 * 4));
    int* SS3 = (int*)(ws + alloc((size_t)cE3 * 4));
    int* SD3 = (int*)(ws + alloc((size_t)cE3 * 4));
    int* DOFF1 = (int*)(ws + alloc((size_t)cN1 * 4));
    int* DOFF2 = (int*)(ws + alloc((size_t)cN2 * 4));
    int* DOFF3 = (int*)(ws + alloc((size_t)cN3 * 4));
    int* CNT1 = (int*)(ws + alloc((size_t)cN1 * 4));
    int* CNT2 = (int*)(ws + alloc((size_t)cN2 * 4));
    int* CNT3 = (int*)(ws + alloc((size_t)cN3 * 4));
    int* CUR  = (int*)(ws + alloc((size_t)cN1 * 4));
    int* PC2  = (int*)(ws + alloc((size_t)cN2 * 4));
    int* PC3  = (int*)(ws + alloc((size_t)cN3 * 4));
    int* PART = (int*)(ws + alloc(1024 * 4));
    _Float16* W1T = (_Float16*)(ws + alloc((size_t)32 * 1024 * 2));
    float* YB = GATH;  // r4 output aliases pool scratch (free by then)

    auto run_scan = [&](const int* in, int* outp, int n) {
        int nb = (n + 1023) / 1024;
        scan1<<<nb, 1024, 0, stream>>>(in, outp, nb > 1 ? PART : nullptr, n);
        if (nb > 1) {
            scan1<<<1, 1024, 0, stream>>>(PART, PART, nullptr, nb);
            scan_add<<<nb, 1024, 0, stream>>>(outp, PART, n);
        }
    };

    // ---- dst-degree counts + dst-sort (CSR) for all three edge lists ----
    hipMemsetAsync(CNT1, 0, (size_t)cN1 * 4, stream);
    hipMemsetAsync(CNT2, 0, (size_t)cN2 * 4, stream);
    hipMemsetAsync(CNT3, 0, (size_t)cN3 * 4, stream);
    count_idx<<<ceil_div(cE1, 256), 256, 0, stream>>>(ei1 + cE1, cE1, CNT1);
    count_idx<<<ceil_div(cE2, 256), 256, 0, stream>>>(ei2 + cE2, cE2, CNT2);
    count_idx<<<ceil_div(cE3, 256), 256, 0, stream>>>(ei3 + cE3, cE3, CNT3);
    run_scan(CNT1, DOFF1, cN1);
    run_scan(CNT2, DOFF2, cN2);
    run_scan(CNT3, DOFF3, cN3);
    hipMemsetAsync(CUR, 0, (size_t)cN1 * 4, stream);
    scatter_edges<<<ceil_div(cE1, 256), 256, 0, stream>>>(ei1, ei1 + cE1, cE1, DOFF1, CUR, SS1, SD1);
    hipMemsetAsync(CUR, 0, (size_t)cN2 * 4, stream);
    scatter_edges<<<ceil_div(cE2, 256), 256, 0, stream>>>(ei2, ei2 + cE2, cE2, DOFF2, CUR, SS2, SD2);
    hipMemsetAsync(CUR, 0, (size_t)cN3 * 4, stream);
    scatter_edges<<<ceil_div(cE3, 256), 256, 0, stream>>>(ei3, ei3 + cE3, cE3, DOFF3, CUR, SS3, SD3);

    // fc1 weights -> fp16 transposed
    w1_to_f16t<<<ceil_div(32 * 1024, 256), 256, 0, stream>>>(fc1_w, W1T);

    auto feast = [&](const float* xin, int ldx, const int* ridx, int n, int cin, int outC,
                     const int* ss, const int* sd, const int* doff, const int* cnt, int E,
                     const float* const* L, float* dstp, int ldo, int col0, int act) {
        // xu = xin @ u  [n, 9]  (fp16 compact, stride QLD)
        gemm_mfma<_Float16><<<dim3(1, ceil_div(n, 64)), 256, 0, stream>>>(
            xin, ldx, ridx, L[0], NH, XUH, QLD, n, NH, cin);
        // xw = xin @ W  [n, 9*outC]  (fp16)
        int NC = NH * outC;
        gemm_mfma<_Float16><<<dim3(ceil_div(NC, 64), ceil_div(n, 64)), 256, 0, stream>>>(
            xin, ldx, ridx, L[2], NC, XWH, NC, n, NC, cin);
        // per-edge softmax with 1/(deg+1) folded
        q_kernel2<<<ceil_div(E, 256), 256, 0, stream>>>(ss, sd, E, XUH, L[1], cnt, Q);
        // CSR aggregate + self-loop + bias + act, fused
        launch_aggfin(outC, doff, cnt, ss, Q, XWH, L[1], L[3], dstp, n, ldo, col0, act, stream);
    };

    // l1: [N1,6] -> [N1,32] into X1CAT[:, 0:32]
    feast(x, 6, nullptr, cN1, 6, 32, SS1, SD1, DOFF1, CNT1, cE1, lp[0], X1CAT, 64, 0, 1);

    // pool -> [N2,32] in GATH
    hipMemsetAsync(PC2, 0, (size_t)cN2 * 4, stream);
    hipMemsetAsync(GATH, 0, (size_t)cN2 * 32 * 4, stream);
    count_idx<<<ceil_div(cN1, 256), 256, 0, stream>>>(clust2, cN1, PC2);
    pool_scatter<<<ceil_div((size_t)cN1 * 32, 256), 256, 0, stream>>>(X1CAT, 64, clust2, GATH, 32, cN1);
    pool_div<<<ceil_div((size_t)cN2 * 32, 256), 256, 0, stream>>>(GATH, PC2, 32, cN2);

    // l2: [N2,32] -> [N2,64] into X2CAT[:, 0:64]
    feast(GATH, 32, nullptr, cN2, 32, 64, SS2, SD2, DOFF2, CNT2, cE2, lp[1], X2CAT, 128, 0, 1);

    // pool -> [N3,64] in GATH
    hipMemsetAsync(PC3, 0, (size_t)cN3 * 4, stream);
    hipMemsetAsync(GATH, 0, (size_t)cN3 * 64 * 4, stream);
    count_idx<<<ceil_div(cN2, 256), 256, 0, stream>>>(clust3, cN2, PC3);
    pool_scatter<<<ceil_div((size_t)cN2 * 64, 256), 256, 0, stream>>>(X2CAT, 128, clust3, GATH, 64, cN2);
    pool_div<<<ceil_div((size_t)cN3 * 64, 256), 256, 0, stream>>>(GATH, PC3, 64, cN3);

    // l3: [N3,64] -> [N3,128] into X3
    feast(GATH, 64, nullptr, cN3, 64, 128, SS3, SD3, DOFF3, CNT3, cE3, lp[2], X3, 128, 0, 1);
    // l4: [N3,128] -> [N3,128] in-place (X3 consumed by gemms before aggfin writes)
    feast(X3, 128, nullptr, cN3, 128, 128, SS3, SD3, DOFF3, CNT3, cE3, lp[3], X3, 128, 0, 1);

    // r1: feast over unpooled x3 (gather fused via ridx=clust3) -> X2CAT[:, 64:128] (no act)
    feast(X3, 128, clust3, cN2, 128, 64, SS2, SD2, DOFF2, CNT2, cE2, lp[4], X2CAT, 128, 64, 0);

    // r2: [N2,128] -> [N2,64] into X2B
    feast(X2CAT, 128, nullptr, cN2, 128, 64, SS2, SD2, DOFF2, CNT2, cE2, lp[5], X2B, 64, 0, 1);

    // r3: feast over unpooled x2 (gather fused via ridx=clust2) -> X1CAT[:, 32:64] (no act)
    feast(X2B, 64, clust2, cN1, 64, 32, SS1, SD1, DOFF1, CNT1, cE1, lp[6], X1CAT, 64, 32, 0);

    // r4: [N1,64] -> [N1,32] into YB
    feast(X1CAT, 64, nullptr, cN1, 64, 32, SS1, SD1, DOFF1, CNT1, cE1, lp[7], YB, 32, 0, 1);

    // fused FC head + normalize (f16 MFMA)
    fc_head2<<<ceil_div(cN1, 64), 256, 0, stream>>>(YB, W1T, fc1_b, fc2_w, fc2_b, out, cN1);

    (void)in_sizes; (void)n_in; (void)out_size; (void)ws_size;
}